// Round 7
// baseline (1702.223 us; speedup 1.0000x reference)
//
#include <hip/hip_runtime.h>
#include <math.h>

#define NN 50000
#define NE 800000
#define NG 512
#define NET (NE + NN)   // edges + self loops
#define NCH ((NN + 511) / 512)   // 98 scan chunks per branch
#define NTILE ((NN + 63) / 64)   // 782 64-node tiles

__device__ __forceinline__ float wsum64(float v) {
#pragma unroll
    for (int o = 32; o > 0; o >>= 1) v += __shfl_down(v, o, 64);
    return v;
}

// tanh(x) = 1 - 2/(exp(2x)+1); accuracy ~1e-6, fine vs 1e-2 threshold
__device__ __forceinline__ float fast_tanh(float x) {
    return 1.f - 2.f / (__expf(2.f * x) + 1.f);
}

// ---------------- CSR build (both branches in one launch set) ----------------

__global__ void k_deg(const int* __restrict__ eia, const int* __restrict__ eib,
                      int* __restrict__ cnt2) {
    int e = blockIdx.x * 256 + threadIdx.x;
    if (e >= 2 * NET) return;
    int br = e >= NET;
    int el = e - br * NET;
    const int* ei = br ? eib : eia;
    int d = (el < NE) ? ei[NE + el] : (el - NE);
    atomicAdd(&cnt2[br * NN + d], 1);
}

__global__ void k_scan1(const int* __restrict__ cnt2, int* __restrict__ partial) {
    int b = blockIdx.x;
    int br = b >= NCH, c = b - (br ? NCH : 0);
    int i = c * 512 + threadIdx.x;
    int v = (i < NN) ? cnt2[br * NN + i] : 0;
    __shared__ int sp[8];
    int lane = threadIdx.x & 63, w = threadIdx.x >> 6;
#pragma unroll
    for (int o = 32; o > 0; o >>= 1) v += __shfl_down(v, o, 64);
    if (lane == 0) sp[w] = v;
    __syncthreads();
    if (threadIdx.x == 0) {
        int s = 0;
#pragma unroll
        for (int k = 0; k < 8; k++) s += sp[k];
        partial[b] = s;
    }
}

__global__ void k_scan2(int* __restrict__ partial, int* __restrict__ rowptr2,
                        float* __restrict__ pool) {
    __shared__ int s[2 * NCH];
    int t = threadIdx.x;  // 256
    for (int i = t; i < 4 * NG; i += 256) pool[i] = 0.f;
    for (int i = t; i < 2 * NCH; i += 256) s[i] = partial[i];
    __syncthreads();
    if (t < 2) {
        int run = 0;
        for (int i = 0; i < NCH; i++) { int v = s[t * NCH + i]; s[t * NCH + i] = run; run += v; }
        rowptr2[t * (NN + 1) + NN] = run;
    }
    __syncthreads();
    for (int i = t; i < 2 * NCH; i += 256) partial[i] = s[i];
}

__global__ void k_scan3(const int* __restrict__ cnt2, const int* __restrict__ partial,
                        int* __restrict__ rowptr2, int* __restrict__ cursor2,
                        float* __restrict__ dinv2) {
    __shared__ int s[512];
    int b = blockIdx.x;
    int br = b >= NCH, c = b - (br ? NCH : 0);
    int t = threadIdx.x;
    int i = c * 512 + t;
    int v = (i < NN) ? cnt2[br * NN + i] : 0;
    s[t] = v;
    __syncthreads();
    for (int o = 1; o < 512; o <<= 1) {
        int add = (t >= o) ? s[t - o] : 0;
        __syncthreads();
        s[t] += add;
        __syncthreads();
    }
    if (i < NN) {
        int excl = s[t] - v + partial[b];
        rowptr2[br * (NN + 1) + i] = excl;
        cursor2[br * NN + i] = excl;
        dinv2[br * NN + i] = v > 0 ? rsqrtf((float)v) : 0.f;
    }
}

__global__ void k_scatter(const int* __restrict__ eia, const int* __restrict__ eib,
                          int* __restrict__ cursor2, int* __restrict__ csr2) {
    int e = blockIdx.x * 256 + threadIdx.x;
    if (e >= 2 * NET) return;
    int br = e >= NET;
    int el = e - br * NET;
    const int* ei = br ? eib : eia;
    int s, d;
    if (el < NE) { s = ei[el]; d = ei[NE + el]; } else { s = d = el - NE; }
    int pos = atomicAdd(&cursor2[br * NN + d], 1);
    csr2[br * NET + pos] = s;
}

// ---------------- node-level kernels ----------------

// A = x @ W_gat; alpha_s = A@a_src, alpha_d = A@a_dst
__global__ void k_gat_input(const float* __restrict__ x, const float* __restrict__ Wg,
                            const float* __restrict__ avs, const float* __restrict__ avd,
                            float* __restrict__ A, float* __restrict__ als, float* __restrict__ ald) {
    __shared__ float sW[9 * 64];
    __shared__ float sas[64], sad[64];
    int t = threadIdx.x;
    for (int i = t; i < 9 * 64; i += 256) sW[i] = Wg[i];
    if (t < 64) { sas[t] = avs[t]; sad[t] = avd[t]; }
    __syncthreads();
    int node = blockIdx.x * 4 + (t >> 6);
    int u = t & 63;
    if (node >= NN) return;
    float h = 0.f;
#pragma unroll
    for (int f = 0; f < 9; f++) h += x[node * 9 + f] * sW[f * 64 + u];
    A[node * 64 + u] = h;
    float ps = wsum64(h * sas[u]);
    float pd = wsum64(h * sad[u]);
    if (u == 0) { als[node] = ps; ald[node] = pd; }
}

// GAT single-pass softmax-aggregate (no max-stabilization: |e| small, fp32 safe)
__global__ __launch_bounds__(256) void k_gat_csr(
        const int* __restrict__ rowptr, const int* __restrict__ csr_src,
        const float* __restrict__ als, const float* __restrict__ ald,
        const float* __restrict__ A, const float* __restrict__ bias,
        float* __restrict__ B) {
    int d = blockIdx.x * 4 + (threadIdx.x >> 6);
    int u = threadIdx.x & 63;
    if (d >= NN) return;
    int beg = rowptr[d], end = rowptr[d + 1];
    float ad = ald[d];
    float a0 = 0.f, a1 = 0.f, a2 = 0.f, a3 = 0.f;
    float n0 = 0.f, n1 = 0.f, n2 = 0.f, n3 = 0.f;
    int i = beg;
    for (; i + 4 <= end; i += 4) {
        int s0 = csr_src[i], s1 = csr_src[i + 1], s2 = csr_src[i + 2], s3 = csr_src[i + 3];
        float v0 = als[s0] + ad, v1 = als[s1] + ad, v2 = als[s2] + ad, v3 = als[s3] + ad;
        float w0 = __expf(fmaxf(v0, 0.2f * v0));
        float w1 = __expf(fmaxf(v1, 0.2f * v1));
        float w2 = __expf(fmaxf(v2, 0.2f * v2));
        float w3 = __expf(fmaxf(v3, 0.2f * v3));
        a0 += A[s0 * 64 + u] * w0; n0 += w0;
        a1 += A[s1 * 64 + u] * w1; n1 += w1;
        a2 += A[s2 * 64 + u] * w2; n2 += w2;
        a3 += A[s3 * 64 + u] * w3; n3 += w3;
    }
    for (; i < end; i++) {
        int s = csr_src[i];
        float v = als[s] + ad;
        float w = __expf(fmaxf(v, 0.2f * v));
        a0 += A[s * 64 + u] * w; n0 += w;
    }
    float acc = (a0 + a1) + (a2 + a3);
    float den = (n0 + n1) + (n2 + n3);
    B[d * 64 + u] = fast_tanh(acc / den + bias[u]);
}

// Dense Y = X @ W (64x64), 64-node tiles, per-thread 16-node accumulators.
// All LDS reads are wave-uniform broadcasts (sX) or lane-consecutive (sW).
__global__ __launch_bounds__(256) void k_lin_tile(
        const float* __restrict__ X, const float* __restrict__ W, float* __restrict__ Y) {
    __shared__ float sW[64 * 64];
    __shared__ float sX[64 * 64];
    int t = threadIdx.x;
    for (int i = t; i < 4096; i += 256) sW[i] = W[i];
    int base = blockIdx.x * 64;
    for (int i = t; i < 4096; i += 256) {
        int n = i >> 6;
        sX[i] = (base + n < NN) ? X[(base + n) * 64 + (i & 63)] : 0.f;
    }
    __syncthreads();
    int u = t & 63, w = t >> 6;
    float acc[16];
#pragma unroll
    for (int j = 0; j < 16; j++) acc[j] = 0.f;
#pragma unroll
    for (int k = 0; k < 64; k += 4) {
        float w0 = sW[k * 64 + u], w1 = sW[(k + 1) * 64 + u];
        float w2 = sW[(k + 2) * 64 + u], w3 = sW[(k + 3) * 64 + u];
#pragma unroll
        for (int j = 0; j < 16; j++) {
            float4 xv = *(const float4*)&sX[(w + 4 * j) * 64 + k];
            acc[j] += xv.x * w0 + xv.y * w1 + xv.z * w2 + xv.w * w3;
        }
    }
#pragma unroll
    for (int j = 0; j < 16; j++) {
        int n = base + w + 4 * j;
        if (n < NN) Y[n * 64 + u] = acc[j];
    }
}

// Lean GCN gather (linear already applied): out = tanh(dinv_d * sum dinv_s*Y[s] + b)
__global__ __launch_bounds__(256) void k_gcn_gather(
        const int* __restrict__ rowptr, const int* __restrict__ csr_src,
        const float* __restrict__ dinv, const float* __restrict__ Y,
        const float* __restrict__ bias, float* __restrict__ Bout) {
    int d = blockIdx.x * 4 + (threadIdx.x >> 6);
    int u = threadIdx.x & 63;
    if (d >= NN) return;
    int beg = rowptr[d], end = rowptr[d + 1];
    float a0 = 0.f, a1 = 0.f, a2 = 0.f, a3 = 0.f;
    int i = beg;
    for (; i + 4 <= end; i += 4) {
        int s0 = csr_src[i], s1 = csr_src[i + 1], s2 = csr_src[i + 2], s3 = csr_src[i + 3];
        a0 += Y[s0 * 64 + u] * dinv[s0];
        a1 += Y[s1 * 64 + u] * dinv[s1];
        a2 += Y[s2 * 64 + u] * dinv[s2];
        a3 += Y[s3 * 64 + u] * dinv[s3];
    }
    for (; i < end; i++) { int s = csr_src[i]; a0 += Y[s * 64 + u] * dinv[s]; }
    float h = ((a0 + a1) + (a2 + a3)) * dinv[d];
    Bout[d * 64 + u] = fast_tanh(h + bias[u]);
}

// MLP (64->64 tanh ->32 tanh ->1) + mean-pool. 64-node tile, no shuffles.
__global__ __launch_bounds__(256) void k_mlp_pool(
        const float* __restrict__ X, const int* __restrict__ batch,
        const float* __restrict__ W1, const float* __restrict__ b1,
        const float* __restrict__ W2, const float* __restrict__ b2,
        const float* __restrict__ W3, const float* __restrict__ b3,
        float* __restrict__ sums, float* __restrict__ cnts) {
    __shared__ float sW1[64 * 64];
    __shared__ float sW2[64 * 32];
    __shared__ float sXY[64 * 64];    // X tile, then reused as Y1 tile
    __shared__ float sY2T[32 * 65];   // transposed, padded (conflict-free col reads)
    __shared__ float sW3[32], sb1[64], sb2[32];
    int t = threadIdx.x;
    for (int i = t; i < 4096; i += 256) sW1[i] = W1[i];
    for (int i = t; i < 2048; i += 256) sW2[i] = W2[i];
    if (t < 64) sb1[t] = b1[t];
    if (t < 32) { sW3[t] = W3[t]; sb2[t] = b2[t]; }
    float bb3 = b3[0];
    int base = blockIdx.x * 64;
    for (int i = t; i < 4096; i += 256) {
        int n = i >> 6;
        sXY[i] = (base + n < NN) ? X[(base + n) * 64 + (i & 63)] : 0.f;
    }
    __syncthreads();
    int u = t & 63, w = t >> 6;
    // layer 1: 64 -> 64, per-thread 16 nodes
    float acc[16];
#pragma unroll
    for (int j = 0; j < 16; j++) acc[j] = sb1[u];
#pragma unroll
    for (int k = 0; k < 64; k += 4) {
        float w0 = sW1[k * 64 + u], w1 = sW1[(k + 1) * 64 + u];
        float w2 = sW1[(k + 2) * 64 + u], w3 = sW1[(k + 3) * 64 + u];
#pragma unroll
        for (int j = 0; j < 16; j++) {
            float4 xv = *(const float4*)&sXY[(w + 4 * j) * 64 + k];
            acc[j] += xv.x * w0 + xv.y * w1 + xv.z * w2 + xv.w * w3;
        }
    }
    __syncthreads();  // all reads of X tile done
#pragma unroll
    for (int j = 0; j < 16; j++) sXY[(w + 4 * j) * 64 + u] = fast_tanh(acc[j]);
    __syncthreads();
    // layer 2: 64 -> 32, thread = (f, n-group of 8)
    int f = t & 31, g8 = t >> 5;
    float acc2[8];
#pragma unroll
    for (int j = 0; j < 8; j++) acc2[j] = sb2[f];
#pragma unroll
    for (int k = 0; k < 64; k += 4) {
        float w0 = sW2[k * 32 + f], w1 = sW2[(k + 1) * 32 + f];
        float w2 = sW2[(k + 2) * 32 + f], w3 = sW2[(k + 3) * 32 + f];
#pragma unroll
        for (int j = 0; j < 8; j++) {
            float4 xv = *(const float4*)&sXY[(g8 + 8 * j) * 64 + k];
            acc2[j] += xv.x * w0 + xv.y * w1 + xv.z * w2 + xv.w * w3;
        }
    }
#pragma unroll
    for (int j = 0; j < 8; j++)
        sY2T[f * 65 + g8 + 8 * j] = fast_tanh(acc2[j]) * sW3[f];
    __syncthreads();
    // layer 3 (sum of 32) + pool: thread = node
    if (t < 64) {
        int node = base + t;
        if (node < NN) {
            float s0 = 0.f, s1 = 0.f, s2 = 0.f, s3 = 0.f;
#pragma unroll
            for (int j = 0; j < 32; j += 4) {
                s0 += sY2T[j * 65 + t];       s1 += sY2T[(j + 1) * 65 + t];
                s2 += sY2T[(j + 2) * 65 + t]; s3 += sY2T[(j + 3) * 65 + t];
            }
            float p = (s0 + s1) + (s2 + s3) + bb3;
            int g = batch[node];
            atomicAdd(&sums[g], p);
            atomicAdd(&cnts[g], 1.f);
        }
    }
}

// pool layout: [sa(NG), ca(NG), sb(NG), cb(NG)]
__global__ void k_final(const float* __restrict__ pool, float* __restrict__ out) {
    int g = blockIdx.x * 256 + threadIdx.x;
    if (g >= NG) return;
    float ua = pool[g] / fmaxf(pool[NG + g], 1.f);
    float ub = pool[2 * NG + g] / fmaxf(pool[3 * NG + g], 1.f);
    float z = ub - ua;
    out[g] = 1.f / (1.f + __expf(-z));
}

struct Params {
    const float *Wg, *avs, *avd, *bg, *Wgcn, *bgcn, *W1, *b1, *W2, *b2, *W3, *b3;
};

static void run_branch(const float* x, const int* batch, const Params& P,
                       const int* rowptr, const int* csr, const float* dinv,
                       float* A, float* B, float* als, float* ald,
                       float* psum, float* pcnt, hipStream_t st) {
    dim3 blk(256);
    const int gNode4 = (NN + 3) / 4;

    k_gat_input<<<gNode4, blk, 0, st>>>(x, P.Wg, P.avs, P.avd, A, als, ald);
    k_gat_csr<<<gNode4, blk, 0, st>>>(rowptr, csr, als, ald, A, P.bg, B);
    // GCN layer l: lin first (associativity), then lean gather
    k_lin_tile<<<NTILE, blk, 0, st>>>(B, P.Wgcn, A);
    k_gcn_gather<<<gNode4, blk, 0, st>>>(rowptr, csr, dinv, A, P.bgcn, B);
    k_lin_tile<<<NTILE, blk, 0, st>>>(B, P.Wgcn + 64 * 64, A);
    k_gcn_gather<<<gNode4, blk, 0, st>>>(rowptr, csr, dinv, A, P.bgcn + 64, B);
    k_mlp_pool<<<NTILE, blk, 0, st>>>(B, batch, P.W1, P.b1, P.W2, P.b2, P.W3, P.b3,
                                      psum, pcnt);
}

extern "C" void kernel_launch(void* const* d_in, const int* in_sizes, int n_in,
                              void* d_out, int out_size, void* d_ws, size_t ws_size,
                              hipStream_t stream) {
    const float* x_a = (const float*)d_in[0];
    const float* x_b = (const float*)d_in[1];
    const int* ei_a = (const int*)d_in[2];
    const int* ei_b = (const int*)d_in[3];
    const int* batch_a = (const int*)d_in[4];
    const int* batch_b = (const int*)d_in[5];
    Params P;
    P.Wg  = (const float*)d_in[6];
    P.avs = (const float*)d_in[7];
    P.avd = (const float*)d_in[8];
    P.bg  = (const float*)d_in[9];
    P.Wgcn = (const float*)d_in[10];
    P.bgcn = (const float*)d_in[11];
    P.W1 = (const float*)d_in[12];
    P.b1 = (const float*)d_in[13];
    P.W2 = (const float*)d_in[14];
    P.b2 = (const float*)d_in[15];
    P.W3 = (const float*)d_in[16];
    P.b3 = (const float*)d_in[17];

    float* ws = (float*)d_ws;
    float* A     = ws;                  // NN*64
    float* B     = A + NN * 64;         // NN*64
    float* als   = B + NN * 64;         // NN
    float* ald   = als + NN;            // NN
    float* dinv2 = ald + NN;            // 2*NN
    float* pool  = dinv2 + 2 * NN;      // 4*NG
    int* cnt2    = (int*)(pool + 4 * NG);   // 2*NN
    int* rowptr2 = cnt2 + 2 * NN;           // 2*(NN+1)
    int* cursor2 = rowptr2 + 2 * (NN + 1);  // 2*NN
    int* partial = cursor2 + 2 * NN;        // 2*NCH
    int* csr2    = partial + 2 * NCH;       // 2*NET

    dim3 blk(256);
    const int gE2 = (2 * NET + 255) / 256;

    hipMemsetAsync(cnt2, 0, 2 * NN * sizeof(int), stream);
    k_deg<<<gE2, blk, 0, stream>>>(ei_a, ei_b, cnt2);
    k_scan1<<<2 * NCH, dim3(512), 0, stream>>>(cnt2, partial);
    k_scan2<<<1, blk, 0, stream>>>(partial, rowptr2, pool);
    k_scan3<<<2 * NCH, dim3(512), 0, stream>>>(cnt2, partial, rowptr2, cursor2, dinv2);
    k_scatter<<<gE2, blk, 0, stream>>>(ei_a, ei_b, cursor2, csr2);

    run_branch(x_a, batch_a, P, rowptr2, csr2, dinv2,
               A, B, als, ald, pool, pool + NG, stream);
    run_branch(x_b, batch_b, P, rowptr2 + (NN + 1), csr2 + NET, dinv2 + NN,
               A, B, als, ald, pool + 2 * NG, pool + 3 * NG, stream);
    k_final<<<(NG + 255) / 256, blk, 0, stream>>>(pool, (float*)d_out);
}

// Round 8
// 775.328 us; speedup vs baseline: 2.1955x; 2.1955x over previous
//
#include <hip/hip_runtime.h>
#include <math.h>

#define NN 50000
#define NE 800000
#define NG 512
#define NET (NE + NN)   // edges + self loops
#define NCH ((NN + 511) / 512)   // 98 scan chunks per branch
#define NTILE ((NN + 63) / 64)   // 782 64-node tiles
#define XS 68                    // padded LDS stride for transposed tiles

__device__ __forceinline__ float wsum64(float v) {
#pragma unroll
    for (int o = 32; o > 0; o >>= 1) v += __shfl_down(v, o, 64);
    return v;
}

// tanh(x) = 1 - 2/(exp(2x)+1); accuracy ~1e-6, fine vs 1e-2 threshold
__device__ __forceinline__ float fast_tanh(float x) {
    return 1.f - 2.f / (__expf(2.f * x) + 1.f);
}

// ---------------- CSR build (both branches in one launch set) ----------------

__global__ void k_deg(const int* __restrict__ eia, const int* __restrict__ eib,
                      int* __restrict__ cnt2) {
    int e = blockIdx.x * 256 + threadIdx.x;
    if (e >= 2 * NET) return;
    int br = e >= NET;
    int el = e - br * NET;
    const int* ei = br ? eib : eia;
    int d = (el < NE) ? ei[NE + el] : (el - NE);
    atomicAdd(&cnt2[br * NN + d], 1);
}

__global__ void k_scan1(const int* __restrict__ cnt2, int* __restrict__ partial) {
    int b = blockIdx.x;
    int br = b >= NCH, c = b - (br ? NCH : 0);
    int i = c * 512 + threadIdx.x;
    int v = (i < NN) ? cnt2[br * NN + i] : 0;
    __shared__ int sp[8];
    int lane = threadIdx.x & 63, w = threadIdx.x >> 6;
#pragma unroll
    for (int o = 32; o > 0; o >>= 1) v += __shfl_down(v, o, 64);
    if (lane == 0) sp[w] = v;
    __syncthreads();
    if (threadIdx.x == 0) {
        int s = 0;
#pragma unroll
        for (int k = 0; k < 8; k++) s += sp[k];
        partial[b] = s;
    }
}

__global__ void k_scan2(int* __restrict__ partial, int* __restrict__ rowptr2,
                        float* __restrict__ pool) {
    __shared__ int s[2 * NCH];
    int t = threadIdx.x;  // 256
    for (int i = t; i < 4 * NG; i += 256) pool[i] = 0.f;
    for (int i = t; i < 2 * NCH; i += 256) s[i] = partial[i];
    __syncthreads();
    if (t < 2) {
        int run = 0;
        for (int i = 0; i < NCH; i++) { int v = s[t * NCH + i]; s[t * NCH + i] = run; run += v; }
        rowptr2[t * (NN + 1) + NN] = run;
    }
    __syncthreads();
    for (int i = t; i < 2 * NCH; i += 256) partial[i] = s[i];
}

__global__ void k_scan3(const int* __restrict__ cnt2, const int* __restrict__ partial,
                        int* __restrict__ rowptr2, int* __restrict__ cursor2,
                        float* __restrict__ dinv2) {
    __shared__ int s[512];
    int b = blockIdx.x;
    int br = b >= NCH, c = b - (br ? NCH : 0);
    int t = threadIdx.x;
    int i = c * 512 + t;
    int v = (i < NN) ? cnt2[br * NN + i] : 0;
    s[t] = v;
    __syncthreads();
    for (int o = 1; o < 512; o <<= 1) {
        int add = (t >= o) ? s[t - o] : 0;
        __syncthreads();
        s[t] += add;
        __syncthreads();
    }
    if (i < NN) {
        int excl = s[t] - v + partial[b];
        rowptr2[br * (NN + 1) + i] = excl;
        cursor2[br * NN + i] = excl;
        dinv2[br * NN + i] = v > 0 ? rsqrtf((float)v) : 0.f;
    }
}

__global__ void k_scatter(const int* __restrict__ eia, const int* __restrict__ eib,
                          int* __restrict__ cursor2, int* __restrict__ csr2) {
    int e = blockIdx.x * 256 + threadIdx.x;
    if (e >= 2 * NET) return;
    int br = e >= NET;
    int el = e - br * NET;
    const int* ei = br ? eib : eia;
    int s, d;
    if (el < NE) { s = ei[el]; d = ei[NE + el]; } else { s = d = el - NE; }
    int pos = atomicAdd(&cursor2[br * NN + d], 1);
    csr2[br * NET + pos] = s;
}

// ---------------- node-level kernels ----------------

// A = x @ W_gat; alpha_s = A@a_src, alpha_d = A@a_dst
__global__ void k_gat_input(const float* __restrict__ x, const float* __restrict__ Wg,
                            const float* __restrict__ avs, const float* __restrict__ avd,
                            float* __restrict__ A, float* __restrict__ als, float* __restrict__ ald) {
    __shared__ float sW[9 * 64];
    __shared__ float sas[64], sad[64];
    int t = threadIdx.x;
    for (int i = t; i < 9 * 64; i += 256) sW[i] = Wg[i];
    if (t < 64) { sas[t] = avs[t]; sad[t] = avd[t]; }
    __syncthreads();
    int node = blockIdx.x * 4 + (t >> 6);
    int u = t & 63;
    if (node >= NN) return;
    float h = 0.f;
#pragma unroll
    for (int f = 0; f < 9; f++) h += x[node * 9 + f] * sW[f * 64 + u];
    A[node * 64 + u] = h;
    float ps = wsum64(h * sas[u]);
    float pd = wsum64(h * sad[u]);
    if (u == 0) { als[node] = ps; ald[node] = pd; }
}

// GAT single-pass softmax-aggregate (no max-stabilization: |e| small, fp32 safe)
__global__ __launch_bounds__(256) void k_gat_csr(
        const int* __restrict__ rowptr, const int* __restrict__ csr_src,
        const float* __restrict__ als, const float* __restrict__ ald,
        const float* __restrict__ A, const float* __restrict__ bias,
        float* __restrict__ B) {
    int d = blockIdx.x * 4 + (threadIdx.x >> 6);
    int u = threadIdx.x & 63;
    if (d >= NN) return;
    int beg = rowptr[d], end = rowptr[d + 1];
    float ad = ald[d];
    float a0 = 0.f, a1 = 0.f, a2 = 0.f, a3 = 0.f;
    float n0 = 0.f, n1 = 0.f, n2 = 0.f, n3 = 0.f;
    int i = beg;
    for (; i + 4 <= end; i += 4) {
        int s0 = csr_src[i], s1 = csr_src[i + 1], s2 = csr_src[i + 2], s3 = csr_src[i + 3];
        float v0 = als[s0] + ad, v1 = als[s1] + ad, v2 = als[s2] + ad, v3 = als[s3] + ad;
        float w0 = __expf(fmaxf(v0, 0.2f * v0));
        float w1 = __expf(fmaxf(v1, 0.2f * v1));
        float w2 = __expf(fmaxf(v2, 0.2f * v2));
        float w3 = __expf(fmaxf(v3, 0.2f * v3));
        a0 += A[s0 * 64 + u] * w0; n0 += w0;
        a1 += A[s1 * 64 + u] * w1; n1 += w1;
        a2 += A[s2 * 64 + u] * w2; n2 += w2;
        a3 += A[s3 * 64 + u] * w3; n3 += w3;
    }
    for (; i < end; i++) {
        int s = csr_src[i];
        float v = als[s] + ad;
        float w = __expf(fmaxf(v, 0.2f * v));
        a0 += A[s * 64 + u] * w; n0 += w;
    }
    float acc = (a0 + a1) + (a2 + a3);
    float den = (n0 + n1) + (n2 + n3);
    B[d * 64 + u] = fast_tanh(acc / den + bias[u]);
}

// Stage 64-node tile transposed into LDS: sXT[feat * XS + node]
__device__ __forceinline__ void load_tile_T(const float* __restrict__ X, int base,
                                            float* sXT, int t) {
    const float4* X4 = (const float4*)X;
    for (int i4 = t; i4 < 1024; i4 += 256) {
        int node = i4 >> 4, fq = (i4 & 15) * 4;
        float4 v;
        if (base + node < NN) v = X4[(size_t)(base + node) * 16 + (i4 & 15)];
        else v = make_float4(0.f, 0.f, 0.f, 0.f);
        sXT[(fq + 0) * XS + node] = v.x;
        sXT[(fq + 1) * XS + node] = v.y;
        sXT[(fq + 2) * XS + node] = v.z;
        sXT[(fq + 3) * XS + node] = v.w;
    }
}

// Dense Y = X @ W (64x64), 64-node tile, 4x4 register blocking (no spills).
__global__ __launch_bounds__(256) void k_lin_tile(
        const float* __restrict__ X, const float* __restrict__ W, float* __restrict__ Y) {
    __shared__ float sW[64 * 64];
    __shared__ float sXT[64 * XS];
    int t = threadIdx.x;
    for (int i = t; i < 4096; i += 256) sW[i] = W[i];
    int base = blockIdx.x * 64;
    load_tile_T(X, base, sXT, t);
    __syncthreads();
    int tx = t & 15, ty = t >> 4;   // features 4*tx.., nodes 4*ty..
    float acc[4][4];
#pragma unroll
    for (int i = 0; i < 4; i++)
#pragma unroll
        for (int j = 0; j < 4; j++) acc[i][j] = 0.f;
#pragma unroll 4
    for (int k = 0; k < 64; k++) {
        float4 wv = *(const float4*)&sW[k * 64 + 4 * tx];
        float4 xv = *(const float4*)&sXT[k * XS + 4 * ty];
        acc[0][0] += xv.x * wv.x; acc[0][1] += xv.x * wv.y; acc[0][2] += xv.x * wv.z; acc[0][3] += xv.x * wv.w;
        acc[1][0] += xv.y * wv.x; acc[1][1] += xv.y * wv.y; acc[1][2] += xv.y * wv.z; acc[1][3] += xv.y * wv.w;
        acc[2][0] += xv.z * wv.x; acc[2][1] += xv.z * wv.y; acc[2][2] += xv.z * wv.z; acc[2][3] += xv.z * wv.w;
        acc[3][0] += xv.w * wv.x; acc[3][1] += xv.w * wv.y; acc[3][2] += xv.w * wv.z; acc[3][3] += xv.w * wv.w;
    }
#pragma unroll
    for (int i = 0; i < 4; i++) {
        int n = base + 4 * ty + i;
        if (n < NN) {
            float4 o = make_float4(acc[i][0], acc[i][1], acc[i][2], acc[i][3]);
            *(float4*)&Y[(size_t)n * 64 + 4 * tx] = o;
        }
    }
}

// Lean GCN gather (linear already applied): out = tanh(dinv_d * sum dinv_s*Y[s] + b)
__global__ __launch_bounds__(256) void k_gcn_gather(
        const int* __restrict__ rowptr, const int* __restrict__ csr_src,
        const float* __restrict__ dinv, const float* __restrict__ Y,
        const float* __restrict__ bias, float* __restrict__ Bout) {
    int d = blockIdx.x * 4 + (threadIdx.x >> 6);
    int u = threadIdx.x & 63;
    if (d >= NN) return;
    int beg = rowptr[d], end = rowptr[d + 1];
    float a0 = 0.f, a1 = 0.f, a2 = 0.f, a3 = 0.f;
    int i = beg;
    for (; i + 4 <= end; i += 4) {
        int s0 = csr_src[i], s1 = csr_src[i + 1], s2 = csr_src[i + 2], s3 = csr_src[i + 3];
        a0 += Y[s0 * 64 + u] * dinv[s0];
        a1 += Y[s1 * 64 + u] * dinv[s1];
        a2 += Y[s2 * 64 + u] * dinv[s2];
        a3 += Y[s3 * 64 + u] * dinv[s3];
    }
    for (; i < end; i++) { int s = csr_src[i]; a0 += Y[s * 64 + u] * dinv[s]; }
    float h = ((a0 + a1) + (a2 + a3)) * dinv[d];
    Bout[d * 64 + u] = fast_tanh(h + bias[u]);
}

// MLP (64->64 tanh ->32 tanh ->1) + mean-pool. 64-node tile, 4x4 blocking.
__global__ __launch_bounds__(256) void k_mlp_pool(
        const float* __restrict__ X, const int* __restrict__ batch,
        const float* __restrict__ W1, const float* __restrict__ b1,
        const float* __restrict__ W2, const float* __restrict__ b2,
        const float* __restrict__ W3, const float* __restrict__ b3,
        float* __restrict__ sums, float* __restrict__ cnts) {
    __shared__ float sW1[64 * 64];
    __shared__ float sW2[64 * 32];
    __shared__ float sXT[64 * XS];   // X tile (transposed); reused for Y1 tile
    __shared__ float sP[64 * 8];     // layer-3 partials
    __shared__ float sW3[32], sb1[64], sb2[32];
    int t = threadIdx.x;
    for (int i = t; i < 4096; i += 256) sW1[i] = W1[i];
    for (int i = t; i < 2048; i += 256) sW2[i] = W2[i];
    if (t < 64) sb1[t] = b1[t];
    if (t < 32) { sW3[t] = W3[t]; sb2[t] = b2[t]; }
    float bb3 = b3[0];
    int base = blockIdx.x * 64;
    load_tile_T(X, base, sXT, t);
    __syncthreads();
    // ---- layer 1: 64 -> 64, 4x4 tile
    int tx = t & 15, ty = t >> 4;
    float acc[4][4];
#pragma unroll
    for (int i = 0; i < 4; i++)
#pragma unroll
        for (int j = 0; j < 4; j++) acc[i][j] = sb1[4 * tx + j];
#pragma unroll 4
    for (int k = 0; k < 64; k++) {
        float4 wv = *(const float4*)&sW1[k * 64 + 4 * tx];
        float4 xv = *(const float4*)&sXT[k * XS + 4 * ty];
        acc[0][0] += xv.x * wv.x; acc[0][1] += xv.x * wv.y; acc[0][2] += xv.x * wv.z; acc[0][3] += xv.x * wv.w;
        acc[1][0] += xv.y * wv.x; acc[1][1] += xv.y * wv.y; acc[1][2] += xv.y * wv.z; acc[1][3] += xv.y * wv.w;
        acc[2][0] += xv.z * wv.x; acc[2][1] += xv.z * wv.y; acc[2][2] += xv.z * wv.z; acc[2][3] += xv.z * wv.w;
        acc[3][0] += xv.w * wv.x; acc[3][1] += xv.w * wv.y; acc[3][2] += xv.w * wv.z; acc[3][3] += xv.w * wv.w;
    }
    __syncthreads();  // all layer-1 reads of sXT done
    // write tanh(acc) back transposed: sXT[feat * XS + node]
#pragma unroll
    for (int i = 0; i < 4; i++)
#pragma unroll
        for (int j = 0; j < 4; j++)
            sXT[(4 * tx + j) * XS + 4 * ty + i] = fast_tanh(acc[i][j]);
    __syncthreads();
    // ---- layer 2: 64 -> 32, 2x4 tile (tx2: 8 feature quads, ty2: 32 node pairs)
    int tx2 = t & 7, ty2 = t >> 3;
    float a2_[2][4];
#pragma unroll
    for (int i = 0; i < 2; i++)
#pragma unroll
        for (int j = 0; j < 4; j++) a2_[i][j] = sb2[4 * tx2 + j];
#pragma unroll 4
    for (int k = 0; k < 64; k++) {
        float4 wv = *(const float4*)&sW2[k * 32 + 4 * tx2];
        float x0 = sXT[k * XS + 2 * ty2];
        float x1 = sXT[k * XS + 2 * ty2 + 1];
        a2_[0][0] += x0 * wv.x; a2_[0][1] += x0 * wv.y; a2_[0][2] += x0 * wv.z; a2_[0][3] += x0 * wv.w;
        a2_[1][0] += x1 * wv.x; a2_[1][1] += x1 * wv.y; a2_[1][2] += x1 * wv.z; a2_[1][3] += x1 * wv.w;
    }
    // ---- layer 3 partials: p = sum_j tanh(y2_j) * W3_j
#pragma unroll
    for (int i = 0; i < 2; i++) {
        float p = fast_tanh(a2_[i][0]) * sW3[4 * tx2]
                + fast_tanh(a2_[i][1]) * sW3[4 * tx2 + 1]
                + fast_tanh(a2_[i][2]) * sW3[4 * tx2 + 2]
                + fast_tanh(a2_[i][3]) * sW3[4 * tx2 + 3];
        sP[(2 * ty2 + i) * 8 + tx2] = p;
    }
    __syncthreads();
    // ---- reduce 8 partials per node + pool
    if (t < 64) {
        int node = base + t;
        if (node < NN) {
            float s0 = sP[t * 8 + 0] + sP[t * 8 + 1] + sP[t * 8 + 2] + sP[t * 8 + 3];
            float s1 = sP[t * 8 + 4] + sP[t * 8 + 5] + sP[t * 8 + 6] + sP[t * 8 + 7];
            float p = s0 + s1 + bb3;
            int g = batch[node];
            atomicAdd(&sums[g], p);
            atomicAdd(&cnts[g], 1.f);
        }
    }
}

// pool layout: [sa(NG), ca(NG), sb(NG), cb(NG)]
__global__ void k_final(const float* __restrict__ pool, float* __restrict__ out) {
    int g = blockIdx.x * 256 + threadIdx.x;
    if (g >= NG) return;
    float ua = pool[g] / fmaxf(pool[NG + g], 1.f);
    float ub = pool[2 * NG + g] / fmaxf(pool[3 * NG + g], 1.f);
    float z = ub - ua;
    out[g] = 1.f / (1.f + __expf(-z));
}

struct Params {
    const float *Wg, *avs, *avd, *bg, *Wgcn, *bgcn, *W1, *b1, *W2, *b2, *W3, *b3;
};

static void run_branch(const float* x, const int* batch, const Params& P,
                       const int* rowptr, const int* csr, const float* dinv,
                       float* A, float* B, float* als, float* ald,
                       float* psum, float* pcnt, hipStream_t st) {
    dim3 blk(256);
    const int gNode4 = (NN + 3) / 4;

    k_gat_input<<<gNode4, blk, 0, st>>>(x, P.Wg, P.avs, P.avd, A, als, ald);
    k_gat_csr<<<gNode4, blk, 0, st>>>(rowptr, csr, als, ald, A, P.bg, B);
    // GCN layer l: lin first (associativity), then lean gather
    k_lin_tile<<<NTILE, blk, 0, st>>>(B, P.Wgcn, A);
    k_gcn_gather<<<gNode4, blk, 0, st>>>(rowptr, csr, dinv, A, P.bgcn, B);
    k_lin_tile<<<NTILE, blk, 0, st>>>(B, P.Wgcn + 64 * 64, A);
    k_gcn_gather<<<gNode4, blk, 0, st>>>(rowptr, csr, dinv, A, P.bgcn + 64, B);
    k_mlp_pool<<<NTILE, blk, 0, st>>>(B, batch, P.W1, P.b1, P.W2, P.b2, P.W3, P.b3,
                                      psum, pcnt);
}

extern "C" void kernel_launch(void* const* d_in, const int* in_sizes, int n_in,
                              void* d_out, int out_size, void* d_ws, size_t ws_size,
                              hipStream_t stream) {
    const float* x_a = (const float*)d_in[0];
    const float* x_b = (const float*)d_in[1];
    const int* ei_a = (const int*)d_in[2];
    const int* ei_b = (const int*)d_in[3];
    const int* batch_a = (const int*)d_in[4];
    const int* batch_b = (const int*)d_in[5];
    Params P;
    P.Wg  = (const float*)d_in[6];
    P.avs = (const float*)d_in[7];
    P.avd = (const float*)d_in[8];
    P.bg  = (const float*)d_in[9];
    P.Wgcn = (const float*)d_in[10];
    P.bgcn = (const float*)d_in[11];
    P.W1 = (const float*)d_in[12];
    P.b1 = (const float*)d_in[13];
    P.W2 = (const float*)d_in[14];
    P.b2 = (const float*)d_in[15];
    P.W3 = (const float*)d_in[16];
    P.b3 = (const float*)d_in[17];

    float* ws = (float*)d_ws;
    float* A     = ws;                  // NN*64
    float* B     = A + NN * 64;         // NN*64
    float* als   = B + NN * 64;         // NN
    float* ald   = als + NN;            // NN
    float* dinv2 = ald + NN;            // 2*NN
    float* pool  = dinv2 + 2 * NN;      // 4*NG
    int* cnt2    = (int*)(pool + 4 * NG);   // 2*NN
    int* rowptr2 = cnt2 + 2 * NN;           // 2*(NN+1)
    int* cursor2 = rowptr2 + 2 * (NN + 1);  // 2*NN
    int* partial = cursor2 + 2 * NN;        // 2*NCH
    int* csr2    = partial + 2 * NCH;       // 2*NET

    dim3 blk(256);
    const int gE2 = (2 * NET + 255) / 256;

    hipMemsetAsync(cnt2, 0, 2 * NN * sizeof(int), stream);
    k_deg<<<gE2, blk, 0, stream>>>(ei_a, ei_b, cnt2);
    k_scan1<<<2 * NCH, dim3(512), 0, stream>>>(cnt2, partial);
    k_scan2<<<1, blk, 0, stream>>>(partial, rowptr2, pool);
    k_scan3<<<2 * NCH, dim3(512), 0, stream>>>(cnt2, partial, rowptr2, cursor2, dinv2);
    k_scatter<<<gE2, blk, 0, stream>>>(ei_a, ei_b, cursor2, csr2);

    run_branch(x_a, batch_a, P, rowptr2, csr2, dinv2,
               A, B, als, ald, pool, pool + NG, stream);
    run_branch(x_b, batch_b, P, rowptr2 + (NN + 1), csr2 + NET, dinv2 + NN,
               A, B, als, ald, pool + 2 * NG, pool + 3 * NG, stream);
    k_final<<<(NG + 255) / 256, blk, 0, stream>>>(pool, (float*)d_out);
}

// Round 9
// 665.794 us; speedup vs baseline: 2.5567x; 1.1645x over previous
//
#include <hip/hip_runtime.h>
#include <hip/hip_fp16.h>
#include <math.h>

#define NN 50000
#define NE 800000
#define NG 512
#define NET (NE + NN)            // edges + self loops
#define NCH ((NN + 511) / 512)   // 98 scan chunks per branch
#define NT2 ((2 * NN + 63) / 64) // 1563 64-node tiles over both branches
#define GN4 ((2 * NN + 3) / 4)   // wave-per-node grids, both branches
#define XS 68                    // padded LDS stride for transposed tiles

typedef unsigned short u16;

__device__ __forceinline__ float wsum64(float v) {
#pragma unroll
    for (int o = 32; o > 0; o >>= 1) v += __shfl_down(v, o, 64);
    return v;
}

__device__ __forceinline__ float fast_tanh(float x) {
    return 1.f - 2.f / (__expf(2.f * x) + 1.f);
}

// ---------------- CSR build (both branches) ----------------

__global__ void k_deg(const int* __restrict__ eia, const int* __restrict__ eib,
                      int* __restrict__ cnt2) {
    int e = blockIdx.x * 256 + threadIdx.x;
    if (e >= 2 * NET) return;
    int br = e >= NET;
    int el = e - br * NET;
    const int* ei = br ? eib : eia;
    int d = (el < NE) ? ei[NE + el] : (el - NE);
    atomicAdd(&cnt2[br * NN + d], 1);
}

__global__ void k_scan1(const int* __restrict__ cnt2, int* __restrict__ partial) {
    int b = blockIdx.x;
    int br = b >= NCH, c = b - (br ? NCH : 0);
    int i = c * 512 + threadIdx.x;
    int v = (i < NN) ? cnt2[br * NN + i] : 0;
    __shared__ int sp[8];
    int lane = threadIdx.x & 63, w = threadIdx.x >> 6;
#pragma unroll
    for (int o = 32; o > 0; o >>= 1) v += __shfl_down(v, o, 64);
    if (lane == 0) sp[w] = v;
    __syncthreads();
    if (threadIdx.x == 0) {
        int s = 0;
#pragma unroll
        for (int k = 0; k < 8; k++) s += sp[k];
        partial[b] = s;
    }
}

__global__ void k_scan2(int* __restrict__ partial, int* __restrict__ rowptr2,
                        float* __restrict__ pool) {
    __shared__ int s[2 * NCH];
    int t = threadIdx.x;  // 256
    for (int i = t; i < 4 * NG; i += 256) pool[i] = 0.f;
    for (int i = t; i < 2 * NCH; i += 256) s[i] = partial[i];
    __syncthreads();
    if (t < 2) {
        int run = 0;
        for (int i = 0; i < NCH; i++) { int v = s[t * NCH + i]; s[t * NCH + i] = run; run += v; }
        rowptr2[t * (NN + 1) + NN] = run;
    }
    __syncthreads();
    for (int i = t; i < 2 * NCH; i += 256) partial[i] = s[i];
}

__global__ void k_scan3(const int* __restrict__ cnt2, const int* __restrict__ partial,
                        int* __restrict__ rowptr2, int* __restrict__ cursor2,
                        float* __restrict__ dinv2) {
    __shared__ int s[512];
    int b = blockIdx.x;
    int br = b >= NCH, c = b - (br ? NCH : 0);
    int t = threadIdx.x;
    int i = c * 512 + t;
    int v = (i < NN) ? cnt2[br * NN + i] : 0;
    s[t] = v;
    __syncthreads();
    for (int o = 1; o < 512; o <<= 1) {
        int add = (t >= o) ? s[t - o] : 0;
        __syncthreads();
        s[t] += add;
        __syncthreads();
    }
    if (i < NN) {
        int excl = s[t] - v + partial[b];
        rowptr2[br * (NN + 1) + i] = excl;
        cursor2[br * NN + i] = excl;
        dinv2[br * NN + i] = v > 0 ? rsqrtf((float)v) : 0.f;
    }
}

__global__ void k_scatter(const int* __restrict__ eia, const int* __restrict__ eib,
                          int* __restrict__ cursor2, u16* __restrict__ csr2) {
    int e = blockIdx.x * 256 + threadIdx.x;
    if (e >= 2 * NET) return;
    int br = e >= NET;
    int el = e - br * NET;
    const int* ei = br ? eib : eia;
    int s, d;
    if (el < NE) { s = ei[el]; d = ei[NE + el]; } else { s = d = el - NE; }
    int pos = atomicAdd(&cursor2[br * NN + d], 1);
    csr2[br * NET + pos] = (u16)s;
}

// ---------------- node-level kernels (both branches, node id in [0,2*NN)) ----

// A = x @ W_gat (fp16 out); alpha_s, alpha_d fp32
__global__ void k_gat_input(const float* __restrict__ xa, const float* __restrict__ xb,
                            const float* __restrict__ Wg,
                            const float* __restrict__ avs, const float* __restrict__ avd,
                            __half* __restrict__ A, float* __restrict__ als,
                            float* __restrict__ ald) {
    __shared__ float sW[9 * 64];
    __shared__ float sas[64], sad[64];
    int t = threadIdx.x;
    for (int i = t; i < 9 * 64; i += 256) sW[i] = Wg[i];
    if (t < 64) { sas[t] = avs[t]; sad[t] = avd[t]; }
    __syncthreads();
    int n = blockIdx.x * 4 + (t >> 6);
    int u = t & 63;
    if (n >= 2 * NN) return;
    const float* xp = (n < NN) ? &xa[(size_t)n * 9] : &xb[(size_t)(n - NN) * 9];
    float h = 0.f;
#pragma unroll
    for (int f = 0; f < 9; f++) h += xp[f] * sW[f * 64 + u];
    A[(size_t)n * 64 + u] = __float2half(h);
    float ps = wsum64(h * sas[u]);
    float pd = wsum64(h * sad[u]);
    if (u == 0) { als[n] = ps; ald[n] = pd; }
}

// GAT single-pass softmax-aggregate (no max-stab: |e|<~25, fp32-safe)
__global__ __launch_bounds__(256) void k_gat_csr(
        const int* __restrict__ rowptr2, const u16* __restrict__ csr2,
        const float* __restrict__ als, const float* __restrict__ ald,
        const __half* __restrict__ A, const float* __restrict__ bias,
        __half* __restrict__ B) {
    int dg = blockIdx.x * 4 + (threadIdx.x >> 6);
    int u = threadIdx.x & 63;
    if (dg >= 2 * NN) return;
    int br = dg >= NN;
    int d = dg - br * NN;
    const int* rp = rowptr2 + br * (NN + 1);
    const u16* cs = csr2 + br * NET;
    int nb = br * NN;
    int beg = rp[d], end = rp[d + 1];
    float ad = ald[dg];
    float a0 = 0.f, a1 = 0.f, a2 = 0.f, a3 = 0.f;
    float n0 = 0.f, n1 = 0.f, n2 = 0.f, n3 = 0.f;
    int i = beg;
    for (; i + 4 <= end; i += 4) {
        int s0 = nb + cs[i], s1 = nb + cs[i + 1], s2 = nb + cs[i + 2], s3 = nb + cs[i + 3];
        float v0 = als[s0] + ad, v1 = als[s1] + ad, v2 = als[s2] + ad, v3 = als[s3] + ad;
        float w0 = __expf(fmaxf(v0, 0.2f * v0));
        float w1 = __expf(fmaxf(v1, 0.2f * v1));
        float w2 = __expf(fmaxf(v2, 0.2f * v2));
        float w3 = __expf(fmaxf(v3, 0.2f * v3));
        a0 += __half2float(A[(size_t)s0 * 64 + u]) * w0; n0 += w0;
        a1 += __half2float(A[(size_t)s1 * 64 + u]) * w1; n1 += w1;
        a2 += __half2float(A[(size_t)s2 * 64 + u]) * w2; n2 += w2;
        a3 += __half2float(A[(size_t)s3 * 64 + u]) * w3; n3 += w3;
    }
    for (; i < end; i++) {
        int s = nb + cs[i];
        float v = als[s] + ad;
        float w = __expf(fmaxf(v, 0.2f * v));
        a0 += __half2float(A[(size_t)s * 64 + u]) * w; n0 += w;
    }
    float acc = (a0 + a1) + (a2 + a3);
    float den = (n0 + n1) + (n2 + n3);
    B[(size_t)dg * 64 + u] = __float2half(fast_tanh(acc / den + bias[u]));
}

// Stage 64-node fp16 tile transposed into LDS: sXT[feat * XS + node]
__device__ __forceinline__ void load_tile_T(const __half* __restrict__ X, int base,
                                            float* sXT, int t) {
    const __half2* X2 = (const __half2*)X;
    for (int i = t; i < 2048; i += 256) {
        int node = i >> 5, p = i & 31;
        float2 v;
        if (base + node < 2 * NN) v = __half22float2(X2[(size_t)(base + node) * 32 + p]);
        else v = make_float2(0.f, 0.f);
        sXT[(2 * p) * XS + node] = v.x;
        sXT[(2 * p + 1) * XS + node] = v.y;
    }
}

// Dense Y = X @ W (64x64), 64-node tile, 4x4 register blocking, fp16 I/O.
__global__ __launch_bounds__(256) void k_lin_tile(
        const __half* __restrict__ X, const float* __restrict__ W, __half* __restrict__ Y) {
    __shared__ float sW[64 * 64];
    __shared__ float sXT[64 * XS];
    int t = threadIdx.x;
    for (int i = t; i < 4096; i += 256) sW[i] = W[i];
    int base = blockIdx.x * 64;
    load_tile_T(X, base, sXT, t);
    __syncthreads();
    int tx = t & 15, ty = t >> 4;
    float acc[4][4];
#pragma unroll
    for (int i = 0; i < 4; i++)
#pragma unroll
        for (int j = 0; j < 4; j++) acc[i][j] = 0.f;
#pragma unroll 4
    for (int k = 0; k < 64; k++) {
        float4 wv = *(const float4*)&sW[k * 64 + 4 * tx];
        float4 xv = *(const float4*)&sXT[k * XS + 4 * ty];
        acc[0][0] += xv.x * wv.x; acc[0][1] += xv.x * wv.y; acc[0][2] += xv.x * wv.z; acc[0][3] += xv.x * wv.w;
        acc[1][0] += xv.y * wv.x; acc[1][1] += xv.y * wv.y; acc[1][2] += xv.y * wv.z; acc[1][3] += xv.y * wv.w;
        acc[2][0] += xv.z * wv.x; acc[2][1] += xv.z * wv.y; acc[2][2] += xv.z * wv.z; acc[2][3] += xv.z * wv.w;
        acc[3][0] += xv.w * wv.x; acc[3][1] += xv.w * wv.y; acc[3][2] += xv.w * wv.z; acc[3][3] += xv.w * wv.w;
    }
#pragma unroll
    for (int i = 0; i < 4; i++) {
        int n = base + 4 * ty + i;
        if (n < 2 * NN) {
            __half2* Y2 = (__half2*)&Y[(size_t)n * 64 + 4 * tx];
            Y2[0] = __floats2half2_rn(acc[i][0], acc[i][1]);
            Y2[1] = __floats2half2_rn(acc[i][2], acc[i][3]);
        }
    }
}

// Lean GCN gather: out = tanh(dinv_d * sum dinv_s*Y[s] + b), fp16 I/O
__global__ __launch_bounds__(256) void k_gcn_gather(
        const int* __restrict__ rowptr2, const u16* __restrict__ csr2,
        const float* __restrict__ dinv, const __half* __restrict__ Y,
        const float* __restrict__ bias, __half* __restrict__ Bout) {
    int dg = blockIdx.x * 4 + (threadIdx.x >> 6);
    int u = threadIdx.x & 63;
    if (dg >= 2 * NN) return;
    int br = dg >= NN;
    int d = dg - br * NN;
    const int* rp = rowptr2 + br * (NN + 1);
    const u16* cs = csr2 + br * NET;
    int nb = br * NN;
    int beg = rp[d], end = rp[d + 1];
    float a0 = 0.f, a1 = 0.f, a2 = 0.f, a3 = 0.f;
    int i = beg;
    for (; i + 4 <= end; i += 4) {
        int s0 = nb + cs[i], s1 = nb + cs[i + 1], s2 = nb + cs[i + 2], s3 = nb + cs[i + 3];
        a0 += __half2float(Y[(size_t)s0 * 64 + u]) * dinv[s0];
        a1 += __half2float(Y[(size_t)s1 * 64 + u]) * dinv[s1];
        a2 += __half2float(Y[(size_t)s2 * 64 + u]) * dinv[s2];
        a3 += __half2float(Y[(size_t)s3 * 64 + u]) * dinv[s3];
    }
    for (; i < end; i++) { int s = nb + cs[i]; a0 += __half2float(Y[(size_t)s * 64 + u]) * dinv[s]; }
    float h = ((a0 + a1) + (a2 + a3)) * dinv[dg];
    Bout[(size_t)dg * 64 + u] = __float2half(fast_tanh(h + bias[u]));
}

// MLP (64->64 tanh ->32 tanh ->1) + mean-pool; 64-node tile, 4x4 blocking.
__global__ __launch_bounds__(256) void k_mlp_pool(
        const __half* __restrict__ X,
        const int* __restrict__ batch_a, const int* __restrict__ batch_b,
        const float* __restrict__ W1, const float* __restrict__ b1,
        const float* __restrict__ W2, const float* __restrict__ b2,
        const float* __restrict__ W3, const float* __restrict__ b3,
        float* __restrict__ pool) {
    __shared__ float sW1[64 * 64];
    __shared__ float sW2[64 * 32];
    __shared__ float sXT[64 * XS];
    __shared__ float sP[64 * 8];
    __shared__ float sW3[32], sb1[64], sb2[32];
    int t = threadIdx.x;
    for (int i = t; i < 4096; i += 256) sW1[i] = W1[i];
    for (int i = t; i < 2048; i += 256) sW2[i] = W2[i];
    if (t < 64) sb1[t] = b1[t];
    if (t < 32) { sW3[t] = W3[t]; sb2[t] = b2[t]; }
    float bb3 = b3[0];
    int base = blockIdx.x * 64;
    load_tile_T(X, base, sXT, t);
    __syncthreads();
    // layer 1: 64 -> 64, 4x4 tile
    int tx = t & 15, ty = t >> 4;
    float acc[4][4];
#pragma unroll
    for (int i = 0; i < 4; i++)
#pragma unroll
        for (int j = 0; j < 4; j++) acc[i][j] = sb1[4 * tx + j];
#pragma unroll 4
    for (int k = 0; k < 64; k++) {
        float4 wv = *(const float4*)&sW1[k * 64 + 4 * tx];
        float4 xv = *(const float4*)&sXT[k * XS + 4 * ty];
        acc[0][0] += xv.x * wv.x; acc[0][1] += xv.x * wv.y; acc[0][2] += xv.x * wv.z; acc[0][3] += xv.x * wv.w;
        acc[1][0] += xv.y * wv.x; acc[1][1] += xv.y * wv.y; acc[1][2] += xv.y * wv.z; acc[1][3] += xv.y * wv.w;
        acc[2][0] += xv.z * wv.x; acc[2][1] += xv.z * wv.y; acc[2][2] += xv.z * wv.z; acc[2][3] += xv.z * wv.w;
        acc[3][0] += xv.w * wv.x; acc[3][1] += xv.w * wv.y; acc[3][2] += xv.w * wv.z; acc[3][3] += xv.w * wv.w;
    }
    __syncthreads();
#pragma unroll
    for (int i = 0; i < 4; i++)
#pragma unroll
        for (int j = 0; j < 4; j++)
            sXT[(4 * tx + j) * XS + 4 * ty + i] = fast_tanh(acc[i][j]);
    __syncthreads();
    // layer 2: 64 -> 32, 2x4 tile
    int tx2 = t & 7, ty2 = t >> 3;
    float a2_[2][4];
#pragma unroll
    for (int i = 0; i < 2; i++)
#pragma unroll
        for (int j = 0; j < 4; j++) a2_[i][j] = sb2[4 * tx2 + j];
#pragma unroll 4
    for (int k = 0; k < 64; k++) {
        float4 wv = *(const float4*)&sW2[k * 32 + 4 * tx2];
        float x0 = sXT[k * XS + 2 * ty2];
        float x1 = sXT[k * XS + 2 * ty2 + 1];
        a2_[0][0] += x0 * wv.x; a2_[0][1] += x0 * wv.y; a2_[0][2] += x0 * wv.z; a2_[0][3] += x0 * wv.w;
        a2_[1][0] += x1 * wv.x; a2_[1][1] += x1 * wv.y; a2_[1][2] += x1 * wv.z; a2_[1][3] += x1 * wv.w;
    }
#pragma unroll
    for (int i = 0; i < 2; i++) {
        float p = fast_tanh(a2_[i][0]) * sW3[4 * tx2]
                + fast_tanh(a2_[i][1]) * sW3[4 * tx2 + 1]
                + fast_tanh(a2_[i][2]) * sW3[4 * tx2 + 2]
                + fast_tanh(a2_[i][3]) * sW3[4 * tx2 + 3];
        sP[(2 * ty2 + i) * 8 + tx2] = p;
    }
    __syncthreads();
    if (t < 64) {
        int n = base + t;
        if (n < 2 * NN) {
            float s0 = sP[t * 8 + 0] + sP[t * 8 + 1] + sP[t * 8 + 2] + sP[t * 8 + 3];
            float s1 = sP[t * 8 + 4] + sP[t * 8 + 5] + sP[t * 8 + 6] + sP[t * 8 + 7];
            float p = s0 + s1 + bb3;
            int br = n >= NN;
            int g = br ? batch_b[n - NN] : batch_a[n];
            float* bin = pool + br * 2 * NG;
            atomicAdd(&bin[g], p);
            atomicAdd(&bin[NG + g], 1.f);
        }
    }
}

// pool layout: [sa(NG), ca(NG), sb(NG), cb(NG)]
__global__ void k_final(const float* __restrict__ pool, float* __restrict__ out) {
    int g = blockIdx.x * 256 + threadIdx.x;
    if (g >= NG) return;
    float ua = pool[g] / fmaxf(pool[NG + g], 1.f);
    float ub = pool[2 * NG + g] / fmaxf(pool[3 * NG + g], 1.f);
    float z = ub - ua;
    out[g] = 1.f / (1.f + __expf(-z));
}

extern "C" void kernel_launch(void* const* d_in, const int* in_sizes, int n_in,
                              void* d_out, int out_size, void* d_ws, size_t ws_size,
                              hipStream_t stream) {
    const float* x_a = (const float*)d_in[0];
    const float* x_b = (const float*)d_in[1];
    const int* ei_a = (const int*)d_in[2];
    const int* ei_b = (const int*)d_in[3];
    const int* batch_a = (const int*)d_in[4];
    const int* batch_b = (const int*)d_in[5];
    const float* Wg   = (const float*)d_in[6];
    const float* avs  = (const float*)d_in[7];
    const float* avd  = (const float*)d_in[8];
    const float* bg   = (const float*)d_in[9];
    const float* Wgcn = (const float*)d_in[10];
    const float* bgcn = (const float*)d_in[11];
    const float* W1 = (const float*)d_in[12];
    const float* b1 = (const float*)d_in[13];
    const float* W2 = (const float*)d_in[14];
    const float* b2 = (const float*)d_in[15];
    const float* W3 = (const float*)d_in[16];
    const float* b3 = (const float*)d_in[17];

    char* w = (char*)d_ws;
    __half* A2 = (__half*)w;          w += (size_t)2 * NN * 64 * 2;
    __half* B2 = (__half*)w;          w += (size_t)2 * NN * 64 * 2;
    float* als2 = (float*)w;          w += (size_t)2 * NN * 4;
    float* ald2 = (float*)w;          w += (size_t)2 * NN * 4;
    float* dinv2 = (float*)w;         w += (size_t)2 * NN * 4;
    float* pool = (float*)w;          w += (size_t)4 * NG * 4;
    int* cnt2 = (int*)w;              w += (size_t)2 * NN * 4;
    int* rowptr2 = (int*)w;           w += (size_t)2 * (NN + 1) * 4;
    int* cursor2 = (int*)w;           w += (size_t)2 * NN * 4;
    int* partial = (int*)w;           w += (size_t)2 * NCH * 4;
    u16* csr2 = (u16*)w;

    dim3 blk(256);
    const int gE2 = (2 * NET + 255) / 256;

    hipMemsetAsync(cnt2, 0, 2 * NN * sizeof(int), stream);
    k_deg<<<gE2, blk, 0, stream>>>(ei_a, ei_b, cnt2);
    k_scan1<<<2 * NCH, dim3(512), 0, stream>>>(cnt2, partial);
    k_scan2<<<1, blk, 0, stream>>>(partial, rowptr2, pool);
    k_scan3<<<2 * NCH, dim3(512), 0, stream>>>(cnt2, partial, rowptr2, cursor2, dinv2);
    k_scatter<<<gE2, blk, 0, stream>>>(ei_a, ei_b, cursor2, csr2);

    k_gat_input<<<GN4, blk, 0, stream>>>(x_a, x_b, Wg, avs, avd, A2, als2, ald2);
    k_gat_csr<<<GN4, blk, 0, stream>>>(rowptr2, csr2, als2, ald2, A2, bg, B2);
    k_lin_tile<<<NT2, blk, 0, stream>>>(B2, Wgcn, A2);
    k_gcn_gather<<<GN4, blk, 0, stream>>>(rowptr2, csr2, dinv2, A2, bgcn, B2);
    k_lin_tile<<<NT2, blk, 0, stream>>>(B2, Wgcn + 64 * 64, A2);
    k_gcn_gather<<<GN4, blk, 0, stream>>>(rowptr2, csr2, dinv2, A2, bgcn + 64, B2);
    k_mlp_pool<<<NT2, blk, 0, stream>>>(B2, batch_a, batch_b, W1, b1, W2, b2, W3, b3, pool);

    k_final<<<(NG + 255) / 256, blk, 0, stream>>>(pool, (float*)d_out);
}

// Round 10
// 632.326 us; speedup vs baseline: 2.6920x; 1.0529x over previous
//
#include <hip/hip_runtime.h>
#include <hip/hip_fp16.h>
#include <math.h>

#define NN 50000
#define NE 800000
#define NG 512
#define NET (NE + NN)            // edges + self loops
#define NCH ((NN + 511) / 512)   // 98 scan chunks per branch
#define NT2 ((2 * NN + 63) / 64) // 1563 64-node tiles over both branches
#define GN4 ((2 * NN + 3) / 4)   // wave-per-node grids, both branches
#define XS 68                    // padded LDS stride for transposed tiles
#define PART 6250                // NN / 8 — dst slice per XCD

typedef unsigned short u16;

__device__ __forceinline__ float wsum64(float v) {
#pragma unroll
    for (int o = 32; o > 0; o >>= 1) v += __shfl_down(v, o, 64);
    return v;
}

__device__ __forceinline__ float fast_tanh(float x) {
    return 1.f - 2.f / (__expf(2.f * x) + 1.f);
}

// ---------------- CSR build (both branches) ----------------

__global__ void k_deg(const int* __restrict__ eia, const int* __restrict__ eib,
                      int* __restrict__ cnt2) {
    int e = blockIdx.x * 256 + threadIdx.x;
    if (e >= 2 * NET) return;
    int br = e >= NET;
    int el = e - br * NET;
    const int* ei = br ? eib : eia;
    int d = (el < NE) ? ei[NE + el] : (el - NE);
    atomicAdd(&cnt2[br * NN + d], 1);
}

__global__ void k_scan1(const int* __restrict__ cnt2, int* __restrict__ partial) {
    int b = blockIdx.x;
    int br = b >= NCH, c = b - (br ? NCH : 0);
    int i = c * 512 + threadIdx.x;
    int v = (i < NN) ? cnt2[br * NN + i] : 0;
    __shared__ int sp[8];
    int lane = threadIdx.x & 63, w = threadIdx.x >> 6;
#pragma unroll
    for (int o = 32; o > 0; o >>= 1) v += __shfl_down(v, o, 64);
    if (lane == 0) sp[w] = v;
    __syncthreads();
    if (threadIdx.x == 0) {
        int s = 0;
#pragma unroll
        for (int k = 0; k < 8; k++) s += sp[k];
        partial[b] = s;
    }
}

__global__ void k_scan2(int* __restrict__ partial, int* __restrict__ rowptr2,
                        float* __restrict__ pool) {
    __shared__ int s[2 * NCH];
    int t = threadIdx.x;  // 256
    for (int i = t; i < 4 * NG; i += 256) pool[i] = 0.f;
    for (int i = t; i < 2 * NCH; i += 256) s[i] = partial[i];
    __syncthreads();
    if (t < 2) {
        int run = 0;
        for (int i = 0; i < NCH; i++) { int v = s[t * NCH + i]; s[t * NCH + i] = run; run += v; }
        rowptr2[t * (NN + 1) + NN] = run;
    }
    __syncthreads();
    for (int i = t; i < 2 * NCH; i += 256) partial[i] = s[i];
}

__global__ void k_scan3(const int* __restrict__ cnt2, const int* __restrict__ partial,
                        int* __restrict__ rowptr2, int* __restrict__ cursor2,
                        float* __restrict__ dinv2) {
    __shared__ int s[512];
    int b = blockIdx.x;
    int br = b >= NCH, c = b - (br ? NCH : 0);
    int t = threadIdx.x;
    int i = c * 512 + t;
    int v = (i < NN) ? cnt2[br * NN + i] : 0;
    s[t] = v;
    __syncthreads();
    for (int o = 1; o < 512; o <<= 1) {
        int add = (t >= o) ? s[t - o] : 0;
        __syncthreads();
        s[t] += add;
        __syncthreads();
    }
    if (i < NN) {
        int excl = s[t] - v + partial[b];
        rowptr2[br * (NN + 1) + i] = excl;
        cursor2[br * NN + i] = excl;
        dinv2[br * NN + i] = v > 0 ? rsqrtf((float)v) : 0.f;
    }
}

// XCD-partitioned scatter: blocks with (blockIdx & 7) == p handle only dst in
// slice p. Under round-robin block->XCD dispatch, slice p's contiguous csr2
// region is written by exactly one XCD's L2 -> each line written back once
// (round-8 profile: unpartitioned scatter wrote 90 MB HBM for 3.4 MB payload).
// Edge-list re-reads (8x) are absorbed by the 256 MB L3. Correct under any
// block->XCD mapping; only locality depends on it.
__global__ __launch_bounds__(256) void k_scatter(
        const int* __restrict__ eia, const int* __restrict__ eib,
        int* __restrict__ cursor2, u16* __restrict__ csr2) {
    int p = blockIdx.x & 7;
    int blk = blockIdx.x >> 3;
    int nblk = gridDim.x >> 3;
    int lo = p * PART, hi = lo + PART;   // NN == 8 * PART exactly
    for (int e = blk * 256 + threadIdx.x; e < 2 * NET; e += nblk * 256) {
        int br = e >= NET;
        int el = e - br * NET;
        const int* ei = br ? eib : eia;
        int d = (el < NE) ? ei[NE + el] : (el - NE);
        if (d >= lo && d < hi) {
            int s = (el < NE) ? ei[el] : d;
            int pos = atomicAdd(&cursor2[br * NN + d], 1);
            csr2[br * NET + pos] = (u16)s;
        }
    }
}

// ---------------- node-level kernels (both branches, node id in [0,2*NN)) ----

// A = x @ W_gat (fp16 out); alpha_s, alpha_d fp32
__global__ void k_gat_input(const float* __restrict__ xa, const float* __restrict__ xb,
                            const float* __restrict__ Wg,
                            const float* __restrict__ avs, const float* __restrict__ avd,
                            __half* __restrict__ A, float* __restrict__ als,
                            float* __restrict__ ald) {
    __shared__ float sW[9 * 64];
    __shared__ float sas[64], sad[64];
    int t = threadIdx.x;
    for (int i = t; i < 9 * 64; i += 256) sW[i] = Wg[i];
    if (t < 64) { sas[t] = avs[t]; sad[t] = avd[t]; }
    __syncthreads();
    int n = blockIdx.x * 4 + (t >> 6);
    int u = t & 63;
    if (n >= 2 * NN) return;
    const float* xp = (n < NN) ? &xa[(size_t)n * 9] : &xb[(size_t)(n - NN) * 9];
    float h = 0.f;
#pragma unroll
    for (int f = 0; f < 9; f++) h += xp[f] * sW[f * 64 + u];
    A[(size_t)n * 64 + u] = __float2half(h);
    float ps = wsum64(h * sas[u]);
    float pd = wsum64(h * sad[u]);
    if (u == 0) { als[n] = ps; ald[n] = pd; }
}

// GAT single-pass softmax-aggregate (no max-stab: |e|<~25, fp32-safe)
__global__ __launch_bounds__(256) void k_gat_csr(
        const int* __restrict__ rowptr2, const u16* __restrict__ csr2,
        const float* __restrict__ als, const float* __restrict__ ald,
        const __half* __restrict__ A, const float* __restrict__ bias,
        __half* __restrict__ B) {
    int dg = blockIdx.x * 4 + (threadIdx.x >> 6);
    int u = threadIdx.x & 63;
    if (dg >= 2 * NN) return;
    int br = dg >= NN;
    int d = dg - br * NN;
    const int* rp = rowptr2 + br * (NN + 1);
    const u16* cs = csr2 + br * NET;
    int nb = br * NN;
    int beg = rp[d], end = rp[d + 1];
    float ad = ald[dg];
    float a0 = 0.f, a1 = 0.f, a2 = 0.f, a3 = 0.f;
    float n0 = 0.f, n1 = 0.f, n2 = 0.f, n3 = 0.f;
    int i = beg;
    for (; i + 4 <= end; i += 4) {
        int s0 = nb + cs[i], s1 = nb + cs[i + 1], s2 = nb + cs[i + 2], s3 = nb + cs[i + 3];
        float v0 = als[s0] + ad, v1 = als[s1] + ad, v2 = als[s2] + ad, v3 = als[s3] + ad;
        float w0 = __expf(fmaxf(v0, 0.2f * v0));
        float w1 = __expf(fmaxf(v1, 0.2f * v1));
        float w2 = __expf(fmaxf(v2, 0.2f * v2));
        float w3 = __expf(fmaxf(v3, 0.2f * v3));
        a0 += __half2float(A[(size_t)s0 * 64 + u]) * w0; n0 += w0;
        a1 += __half2float(A[(size_t)s1 * 64 + u]) * w1; n1 += w1;
        a2 += __half2float(A[(size_t)s2 * 64 + u]) * w2; n2 += w2;
        a3 += __half2float(A[(size_t)s3 * 64 + u]) * w3; n3 += w3;
    }
    for (; i < end; i++) {
        int s = nb + cs[i];
        float v = als[s] + ad;
        float w = __expf(fmaxf(v, 0.2f * v));
        a0 += __half2float(A[(size_t)s * 64 + u]) * w; n0 += w;
    }
    float acc = (a0 + a1) + (a2 + a3);
    float den = (n0 + n1) + (n2 + n3);
    B[(size_t)dg * 64 + u] = __float2half(fast_tanh(acc / den + bias[u]));
}

// Stage 64-node fp16 tile transposed into LDS: sXT[feat * XS + node]
__device__ __forceinline__ void load_tile_T(const __half* __restrict__ X, int base,
                                            float* sXT, int t) {
    const __half2* X2 = (const __half2*)X;
    for (int i = t; i < 2048; i += 256) {
        int node = i >> 5, p = i & 31;
        float2 v;
        if (base + node < 2 * NN) v = __half22float2(X2[(size_t)(base + node) * 32 + p]);
        else v = make_float2(0.f, 0.f);
        sXT[(2 * p) * XS + node] = v.x;
        sXT[(2 * p + 1) * XS + node] = v.y;
    }
}

// Dense Y = X @ W (64x64), 64-node tile, 4x4 register blocking, fp16 I/O.
__global__ __launch_bounds__(256) void k_lin_tile(
        const __half* __restrict__ X, const float* __restrict__ W, __half* __restrict__ Y) {
    __shared__ float sW[64 * 64];
    __shared__ float sXT[64 * XS];
    int t = threadIdx.x;
    for (int i = t; i < 4096; i += 256) sW[i] = W[i];
    int base = blockIdx.x * 64;
    load_tile_T(X, base, sXT, t);
    __syncthreads();
    int tx = t & 15, ty = t >> 4;
    float acc[4][4];
#pragma unroll
    for (int i = 0; i < 4; i++)
#pragma unroll
        for (int j = 0; j < 4; j++) acc[i][j] = 0.f;
#pragma unroll 4
    for (int k = 0; k < 64; k++) {
        float4 wv = *(const float4*)&sW[k * 64 + 4 * tx];
        float4 xv = *(const float4*)&sXT[k * XS + 4 * ty];
        acc[0][0] += xv.x * wv.x; acc[0][1] += xv.x * wv.y; acc[0][2] += xv.x * wv.z; acc[0][3] += xv.x * wv.w;
        acc[1][0] += xv.y * wv.x; acc[1][1] += xv.y * wv.y; acc[1][2] += xv.y * wv.z; acc[1][3] += xv.y * wv.w;
        acc[2][0] += xv.z * wv.x; acc[2][1] += xv.z * wv.y; acc[2][2] += xv.z * wv.z; acc[2][3] += xv.z * wv.w;
        acc[3][0] += xv.w * wv.x; acc[3][1] += xv.w * wv.y; acc[3][2] += xv.w * wv.z; acc[3][3] += xv.w * wv.w;
    }
#pragma unroll
    for (int i = 0; i < 4; i++) {
        int n = base + 4 * ty + i;
        if (n < 2 * NN) {
            __half2* Y2 = (__half2*)&Y[(size_t)n * 64 + 4 * tx];
            Y2[0] = __floats2half2_rn(acc[i][0], acc[i][1]);
            Y2[1] = __floats2half2_rn(acc[i][2], acc[i][3]);
        }
    }
}

// Lean GCN gather: out = tanh(dinv_d * sum dinv_s*Y[s] + b), fp16 I/O
__global__ __launch_bounds__(256) void k_gcn_gather(
        const int* __restrict__ rowptr2, const u16* __restrict__ csr2,
        const float* __restrict__ dinv, const __half* __restrict__ Y,
        const float* __restrict__ bias, __half* __restrict__ Bout) {
    int dg = blockIdx.x * 4 + (threadIdx.x >> 6);
    int u = threadIdx.x & 63;
    if (dg >= 2 * NN) return;
    int br = dg >= NN;
    int d = dg - br * NN;
    const int* rp = rowptr2 + br * (NN + 1);
    const u16* cs = csr2 + br * NET;
    int nb = br * NN;
    int beg = rp[d], end = rp[d + 1];
    float a0 = 0.f, a1 = 0.f, a2 = 0.f, a3 = 0.f;
    int i = beg;
    for (; i + 4 <= end; i += 4) {
        int s0 = nb + cs[i], s1 = nb + cs[i + 1], s2 = nb + cs[i + 2], s3 = nb + cs[i + 3];
        a0 += __half2float(Y[(size_t)s0 * 64 + u]) * dinv[s0];
        a1 += __half2float(Y[(size_t)s1 * 64 + u]) * dinv[s1];
        a2 += __half2float(Y[(size_t)s2 * 64 + u]) * dinv[s2];
        a3 += __half2float(Y[(size_t)s3 * 64 + u]) * dinv[s3];
    }
    for (; i < end; i++) { int s = nb + cs[i]; a0 += __half2float(Y[(size_t)s * 64 + u]) * dinv[s]; }
    float h = ((a0 + a1) + (a2 + a3)) * dinv[dg];
    Bout[(size_t)dg * 64 + u] = __float2half(fast_tanh(h + bias[u]));
}

// MLP (64->64 tanh ->32 tanh ->1) + mean-pool; 64-node tile, 4x4 blocking.
__global__ __launch_bounds__(256) void k_mlp_pool(
        const __half* __restrict__ X,
        const int* __restrict__ batch_a, const int* __restrict__ batch_b,
        const float* __restrict__ W1, const float* __restrict__ b1,
        const float* __restrict__ W2, const float* __restrict__ b2,
        const float* __restrict__ W3, const float* __restrict__ b3,
        float* __restrict__ pool) {
    __shared__ float sW1[64 * 64];
    __shared__ float sW2[64 * 32];
    __shared__ float sXT[64 * XS];
    __shared__ float sP[64 * 8];
    __shared__ float sW3[32], sb1[64], sb2[32];
    int t = threadIdx.x;
    for (int i = t; i < 4096; i += 256) sW1[i] = W1[i];
    for (int i = t; i < 2048; i += 256) sW2[i] = W2[i];
    if (t < 64) sb1[t] = b1[t];
    if (t < 32) { sW3[t] = W3[t]; sb2[t] = b2[t]; }
    float bb3 = b3[0];
    int base = blockIdx.x * 64;
    load_tile_T(X, base, sXT, t);
    __syncthreads();
    // layer 1: 64 -> 64, 4x4 tile
    int tx = t & 15, ty = t >> 4;
    float acc[4][4];
#pragma unroll
    for (int i = 0; i < 4; i++)
#pragma unroll
        for (int j = 0; j < 4; j++) acc[i][j] = sb1[4 * tx + j];
#pragma unroll 4
    for (int k = 0; k < 64; k++) {
        float4 wv = *(const float4*)&sW1[k * 64 + 4 * tx];
        float4 xv = *(const float4*)&sXT[k * XS + 4 * ty];
        acc[0][0] += xv.x * wv.x; acc[0][1] += xv.x * wv.y; acc[0][2] += xv.x * wv.z; acc[0][3] += xv.x * wv.w;
        acc[1][0] += xv.y * wv.x; acc[1][1] += xv.y * wv.y; acc[1][2] += xv.y * wv.z; acc[1][3] += xv.y * wv.w;
        acc[2][0] += xv.z * wv.x; acc[2][1] += xv.z * wv.y; acc[2][2] += xv.z * wv.z; acc[2][3] += xv.z * wv.w;
        acc[3][0] += xv.w * wv.x; acc[3][1] += xv.w * wv.y; acc[3][2] += xv.w * wv.z; acc[3][3] += xv.w * wv.w;
    }
    __syncthreads();
#pragma unroll
    for (int i = 0; i < 4; i++)
#pragma unroll
        for (int j = 0; j < 4; j++)
            sXT[(4 * tx + j) * XS + 4 * ty + i] = fast_tanh(acc[i][j]);
    __syncthreads();
    // layer 2: 64 -> 32, 2x4 tile
    int tx2 = t & 7, ty2 = t >> 3;
    float a2_[2][4];
#pragma unroll
    for (int i = 0; i < 2; i++)
#pragma unroll
        for (int j = 0; j < 4; j++) a2_[i][j] = sb2[4 * tx2 + j];
#pragma unroll 4
    for (int k = 0; k < 64; k++) {
        float4 wv = *(const float4*)&sW2[k * 32 + 4 * tx2];
        float x0 = sXT[k * XS + 2 * ty2];
        float x1 = sXT[k * XS + 2 * ty2 + 1];
        a2_[0][0] += x0 * wv.x; a2_[0][1] += x0 * wv.y; a2_[0][2] += x0 * wv.z; a2_[0][3] += x0 * wv.w;
        a2_[1][0] += x1 * wv.x; a2_[1][1] += x1 * wv.y; a2_[1][2] += x1 * wv.z; a2_[1][3] += x1 * wv.w;
    }
#pragma unroll
    for (int i = 0; i < 2; i++) {
        float p = fast_tanh(a2_[i][0]) * sW3[4 * tx2]
                + fast_tanh(a2_[i][1]) * sW3[4 * tx2 + 1]
                + fast_tanh(a2_[i][2]) * sW3[4 * tx2 + 2]
                + fast_tanh(a2_[i][3]) * sW3[4 * tx2 + 3];
        sP[(2 * ty2 + i) * 8 + tx2] = p;
    }
    __syncthreads();
    if (t < 64) {
        int n = base + t;
        if (n < 2 * NN) {
            float s0 = sP[t * 8 + 0] + sP[t * 8 + 1] + sP[t * 8 + 2] + sP[t * 8 + 3];
            float s1 = sP[t * 8 + 4] + sP[t * 8 + 5] + sP[t * 8 + 6] + sP[t * 8 + 7];
            float p = s0 + s1 + bb3;
            int br = n >= NN;
            int g = br ? batch_b[n - NN] : batch_a[n];
            float* bin = pool + br * 2 * NG;
            atomicAdd(&bin[g], p);
            atomicAdd(&bin[NG + g], 1.f);
        }
    }
}

// pool layout: [sa(NG), ca(NG), sb(NG), cb(NG)]
__global__ void k_final(const float* __restrict__ pool, float* __restrict__ out) {
    int g = blockIdx.x * 256 + threadIdx.x;
    if (g >= NG) return;
    float ua = pool[g] / fmaxf(pool[NG + g], 1.f);
    float ub = pool[2 * NG + g] / fmaxf(pool[3 * NG + g], 1.f);
    float z = ub - ua;
    out[g] = 1.f / (1.f + __expf(-z));
}

extern "C" void kernel_launch(void* const* d_in, const int* in_sizes, int n_in,
                              void* d_out, int out_size, void* d_ws, size_t ws_size,
                              hipStream_t stream) {
    const float* x_a = (const float*)d_in[0];
    const float* x_b = (const float*)d_in[1];
    const int* ei_a = (const int*)d_in[2];
    const int* ei_b = (const int*)d_in[3];
    const int* batch_a = (const int*)d_in[4];
    const int* batch_b = (const int*)d_in[5];
    const float* Wg   = (const float*)d_in[6];
    const float* avs  = (const float*)d_in[7];
    const float* avd  = (const float*)d_in[8];
    const float* bg   = (const float*)d_in[9];
    const float* Wgcn = (const float*)d_in[10];
    const float* bgcn = (const float*)d_in[11];
    const float* W1 = (const float*)d_in[12];
    const float* b1 = (const float*)d_in[13];
    const float* W2 = (const float*)d_in[14];
    const float* b2 = (const float*)d_in[15];
    const float* W3 = (const float*)d_in[16];
    const float* b3 = (const float*)d_in[17];

    char* w = (char*)d_ws;
    __half* A2 = (__half*)w;          w += (size_t)2 * NN * 64 * 2;
    __half* B2 = (__half*)w;          w += (size_t)2 * NN * 64 * 2;
    float* als2 = (float*)w;          w += (size_t)2 * NN * 4;
    float* ald2 = (float*)w;          w += (size_t)2 * NN * 4;
    float* dinv2 = (float*)w;         w += (size_t)2 * NN * 4;
    float* pool = (float*)w;          w += (size_t)4 * NG * 4;
    int* cnt2 = (int*)w;              w += (size_t)2 * NN * 4;
    int* rowptr2 = (int*)w;           w += (size_t)2 * (NN + 1) * 4;
    int* cursor2 = (int*)w;           w += (size_t)2 * NN * 4;
    int* partial = (int*)w;           w += (size_t)2 * NCH * 4;
    u16* csr2 = (u16*)w;

    dim3 blk(256);
    const int gE2 = (2 * NET + 255) / 256;

    hipMemsetAsync(cnt2, 0, 2 * NN * sizeof(int), stream);
    k_deg<<<gE2, blk, 0, stream>>>(ei_a, ei_b, cnt2);
    k_scan1<<<2 * NCH, dim3(512), 0, stream>>>(cnt2, partial);
    k_scan2<<<1, blk, 0, stream>>>(partial, rowptr2, pool);
    k_scan3<<<2 * NCH, dim3(512), 0, stream>>>(cnt2, partial, rowptr2, cursor2, dinv2);
    k_scatter<<<2048, blk, 0, stream>>>(ei_a, ei_b, cursor2, csr2);

    k_gat_input<<<GN4, blk, 0, stream>>>(x_a, x_b, Wg, avs, avd, A2, als2, ald2);
    k_gat_csr<<<GN4, blk, 0, stream>>>(rowptr2, csr2, als2, ald2, A2, bg, B2);
    k_lin_tile<<<NT2, blk, 0, stream>>>(B2, Wgcn, A2);
    k_gcn_gather<<<GN4, blk, 0, stream>>>(rowptr2, csr2, dinv2, A2, bgcn, B2);
    k_lin_tile<<<NT2, blk, 0, stream>>>(B2, Wgcn + 64 * 64, A2);
    k_gcn_gather<<<GN4, blk, 0, stream>>>(rowptr2, csr2, dinv2, A2, bgcn + 64, B2);
    k_mlp_pool<<<NT2, blk, 0, stream>>>(B2, batch_a, batch_b, W1, b1, W2, b2, W3, b3, pool);

    k_final<<<(NG + 255) / 256, blk, 0, stream>>>(pool, (float*)d_out);
}

// Round 11
// 567.428 us; speedup vs baseline: 2.9999x; 1.1144x over previous
//
#include <hip/hip_runtime.h>
#include <hip/hip_fp16.h>
#include <math.h>

#define NN 50000
#define NE 800000
#define NG 512
#define NET (NE + NN)            // edges + self loops
#define NCH ((NN + 511) / 512)   // 98 scan chunks per branch
#define NT2 ((2 * NN + 63) / 64) // 1563 64-node tiles over both branches
#define GN4 ((2 * NN + 3) / 4)   // wave-per-node grids, both branches
#define XS 68                    // node-major LDS stride (x4B: 2-way banks max)
#define PART 6250                // NN / 8 — dst slice per XCD

typedef unsigned short u16;

__device__ __forceinline__ float wsum64(float v) {
#pragma unroll
    for (int o = 32; o > 0; o >>= 1) v += __shfl_down(v, o, 64);
    return v;
}

__device__ __forceinline__ float fast_tanh(float x) {
    return 1.f - 2.f / (__expf(2.f * x) + 1.f);
}

// ---------------- CSR build (both branches) ----------------

__global__ void k_deg(const int* __restrict__ eia, const int* __restrict__ eib,
                      int* __restrict__ cnt2) {
    int e = blockIdx.x * 256 + threadIdx.x;
    if (e >= 2 * NET) return;
    int br = e >= NET;
    int el = e - br * NET;
    const int* ei = br ? eib : eia;
    int d = (el < NE) ? ei[NE + el] : (el - NE);
    atomicAdd(&cnt2[br * NN + d], 1);
}

__global__ void k_scan1(const int* __restrict__ cnt2, int* __restrict__ partial) {
    int b = blockIdx.x;
    int br = b >= NCH, c = b - (br ? NCH : 0);
    int i = c * 512 + threadIdx.x;
    int v = (i < NN) ? cnt2[br * NN + i] : 0;
    __shared__ int sp[8];
    int lane = threadIdx.x & 63, w = threadIdx.x >> 6;
#pragma unroll
    for (int o = 32; o > 0; o >>= 1) v += __shfl_down(v, o, 64);
    if (lane == 0) sp[w] = v;
    __syncthreads();
    if (threadIdx.x == 0) {
        int s = 0;
#pragma unroll
        for (int k = 0; k < 8; k++) s += sp[k];
        partial[b] = s;
    }
}

__global__ void k_scan2(int* __restrict__ partial, int* __restrict__ rowptr2,
                        float* __restrict__ pool) {
    __shared__ int s[2 * NCH];
    int t = threadIdx.x;  // 256
    for (int i = t; i < 4 * NG; i += 256) pool[i] = 0.f;
    for (int i = t; i < 2 * NCH; i += 256) s[i] = partial[i];
    __syncthreads();
    if (t < 2) {
        int run = 0;
        for (int i = 0; i < NCH; i++) { int v = s[t * NCH + i]; s[t * NCH + i] = run; run += v; }
        rowptr2[t * (NN + 1) + NN] = run;
    }
    __syncthreads();
    for (int i = t; i < 2 * NCH; i += 256) partial[i] = s[i];
}

__global__ void k_scan3(const int* __restrict__ cnt2, const int* __restrict__ partial,
                        int* __restrict__ rowptr2, int* __restrict__ cursor2,
                        float* __restrict__ dinv2) {
    __shared__ int s[512];
    int b = blockIdx.x;
    int br = b >= NCH, c = b - (br ? NCH : 0);
    int t = threadIdx.x;
    int i = c * 512 + t;
    int v = (i < NN) ? cnt2[br * NN + i] : 0;
    s[t] = v;
    __syncthreads();
    for (int o = 1; o < 512; o <<= 1) {
        int add = (t >= o) ? s[t - o] : 0;
        __syncthreads();
        s[t] += add;
        __syncthreads();
    }
    if (i < NN) {
        int excl = s[t] - v + partial[b];
        rowptr2[br * (NN + 1) + i] = excl;
        cursor2[br * NN + i] = excl;
        dinv2[br * NN + i] = v > 0 ? rsqrtf((float)v) : 0.f;
    }
}

// XCD-partitioned scatter (see round 9 notes): slice p's csr2 region is only
// dirtied by XCD p's L2 -> lines written back once.
__global__ __launch_bounds__(256) void k_scatter(
        const int* __restrict__ eia, const int* __restrict__ eib,
        int* __restrict__ cursor2, u16* __restrict__ csr2) {
    int p = blockIdx.x & 7;
    int blk = blockIdx.x >> 3;
    int nblk = gridDim.x >> 3;
    int lo = p * PART, hi = lo + PART;
    for (int e = blk * 256 + threadIdx.x; e < 2 * NET; e += nblk * 256) {
        int br = e >= NET;
        int el = e - br * NET;
        const int* ei = br ? eib : eia;
        int d = (el < NE) ? ei[NE + el] : (el - NE);
        if (d >= lo && d < hi) {
            int s = (el < NE) ? ei[el] : d;
            int pos = atomicAdd(&cursor2[br * NN + d], 1);
            csr2[br * NET + pos] = (u16)s;
        }
    }
}

// ---------------- node-level kernels (node id in [0,2*NN)) ----

__global__ void k_gat_input(const float* __restrict__ xa, const float* __restrict__ xb,
                            const float* __restrict__ Wg,
                            const float* __restrict__ avs, const float* __restrict__ avd,
                            __half* __restrict__ A, float* __restrict__ als,
                            float* __restrict__ ald) {
    __shared__ float sW[9 * 64];
    __shared__ float sas[64], sad[64];
    int t = threadIdx.x;
    for (int i = t; i < 9 * 64; i += 256) sW[i] = Wg[i];
    if (t < 64) { sas[t] = avs[t]; sad[t] = avd[t]; }
    __syncthreads();
    int n = blockIdx.x * 4 + (t >> 6);
    int u = t & 63;
    if (n >= 2 * NN) return;
    const float* xp = (n < NN) ? &xa[(size_t)n * 9] : &xb[(size_t)(n - NN) * 9];
    float h = 0.f;
#pragma unroll
    for (int f = 0; f < 9; f++) h += xp[f] * sW[f * 64 + u];
    A[(size_t)n * 64 + u] = __float2half(h);
    float ps = wsum64(h * sas[u]);
    float pd = wsum64(h * sad[u]);
    if (u == 0) { als[n] = ps; ald[n] = pd; }
}

// GAT single-pass softmax-aggregate (no max-stab: |e|<~25, fp32-safe)
__global__ __launch_bounds__(256) void k_gat_csr(
        const int* __restrict__ rowptr2, const u16* __restrict__ csr2,
        const float* __restrict__ als, const float* __restrict__ ald,
        const __half* __restrict__ A, const float* __restrict__ bias,
        __half* __restrict__ B) {
    int dg = blockIdx.x * 4 + (threadIdx.x >> 6);
    int u = threadIdx.x & 63;
    if (dg >= 2 * NN) return;
    int br = dg >= NN;
    int d = dg - br * NN;
    const int* rp = rowptr2 + br * (NN + 1);
    const u16* cs = csr2 + br * NET;
    int nb = br * NN;
    int beg = rp[d], end = rp[d + 1];
    float ad = ald[dg];
    float a0 = 0.f, a1 = 0.f, a2 = 0.f, a3 = 0.f;
    float n0 = 0.f, n1 = 0.f, n2 = 0.f, n3 = 0.f;
    int i = beg;
    for (; i + 4 <= end; i += 4) {
        int s0 = nb + cs[i], s1 = nb + cs[i + 1], s2 = nb + cs[i + 2], s3 = nb + cs[i + 3];
        float v0 = als[s0] + ad, v1 = als[s1] + ad, v2 = als[s2] + ad, v3 = als[s3] + ad;
        float w0 = __expf(fmaxf(v0, 0.2f * v0));
        float w1 = __expf(fmaxf(v1, 0.2f * v1));
        float w2 = __expf(fmaxf(v2, 0.2f * v2));
        float w3 = __expf(fmaxf(v3, 0.2f * v3));
        a0 += __half2float(A[(size_t)s0 * 64 + u]) * w0; n0 += w0;
        a1 += __half2float(A[(size_t)s1 * 64 + u]) * w1; n1 += w1;
        a2 += __half2float(A[(size_t)s2 * 64 + u]) * w2; n2 += w2;
        a3 += __half2float(A[(size_t)s3 * 64 + u]) * w3; n3 += w3;
    }
    for (; i < end; i++) {
        int s = nb + cs[i];
        float v = als[s] + ad;
        float w = __expf(fmaxf(v, 0.2f * v));
        a0 += __half2float(A[(size_t)s * 64 + u]) * w; n0 += w;
    }
    float acc = (a0 + a1) + (a2 + a3);
    float den = (n0 + n1) + (n2 + n3);
    B[(size_t)dg * 64 + u] = __float2half(fast_tanh(acc / den + bias[u]));
}

// Stage 64-node fp16 tile into LDS node-major: sX[node * XS + feat].
// Coalesced global reads (32 lanes sweep one node's 64 feats); LDS float2
// writes at (4*node + 2p) % 32 -> 2-way max (free).
__device__ __forceinline__ void load_tile_NM(const __half* __restrict__ X, int base,
                                             float* sX, int t) {
    const __half2* X2 = (const __half2*)X;
    for (int i = t; i < 2048; i += 256) {
        int node = i >> 5, p = i & 31;
        float2 v;
        if (base + node < 2 * NN) v = __half22float2(X2[(size_t)(base + node) * 32 + p]);
        else v = make_float2(0.f, 0.f);
        *(float2*)&sX[node * XS + 2 * p] = v;
    }
}

// Dense Y = X @ W (64x64), 64-node tile, 4x4 register blocking, node-major
// LDS (conflict-free), fp16 weights in LDS.
__global__ __launch_bounds__(256) void k_lin_tile(
        const __half* __restrict__ X, const float* __restrict__ W, __half* __restrict__ Y) {
    __shared__ __half sW[64 * 64];
    __shared__ float sX[64 * XS];
    int t = threadIdx.x;
    for (int i = t; i < 4096; i += 256) sW[i] = __float2half(W[i]);
    int base = blockIdx.x * 64;
    load_tile_NM(X, base, sX, t);
    __syncthreads();
    int tx = t & 15, ty = t >> 4;   // feats 4*tx.., nodes 4*ty..
    float acc[4][4];
#pragma unroll
    for (int i = 0; i < 4; i++)
#pragma unroll
        for (int j = 0; j < 4; j++) acc[i][j] = 0.f;
#pragma unroll 4
    for (int k = 0; k < 64; k++) {
        const __half2* wp = (const __half2*)&sW[k * 64 + 4 * tx];
        float2 wa = __half22float2(wp[0]);
        float2 wb = __half22float2(wp[1]);
        float x0 = sX[(4 * ty + 0) * XS + k];
        float x1 = sX[(4 * ty + 1) * XS + k];
        float x2 = sX[(4 * ty + 2) * XS + k];
        float x3 = sX[(4 * ty + 3) * XS + k];
        acc[0][0] += x0 * wa.x; acc[0][1] += x0 * wa.y; acc[0][2] += x0 * wb.x; acc[0][3] += x0 * wb.y;
        acc[1][0] += x1 * wa.x; acc[1][1] += x1 * wa.y; acc[1][2] += x1 * wb.x; acc[1][3] += x1 * wb.y;
        acc[2][0] += x2 * wa.x; acc[2][1] += x2 * wa.y; acc[2][2] += x2 * wb.x; acc[2][3] += x2 * wb.y;
        acc[3][0] += x3 * wa.x; acc[3][1] += x3 * wa.y; acc[3][2] += x3 * wb.x; acc[3][3] += x3 * wb.y;
    }
#pragma unroll
    for (int i = 0; i < 4; i++) {
        int n = base + 4 * ty + i;
        if (n < 2 * NN) {
            __half2* Y2 = (__half2*)&Y[(size_t)n * 64 + 4 * tx];
            Y2[0] = __floats2half2_rn(acc[i][0], acc[i][1]);
            Y2[1] = __floats2half2_rn(acc[i][2], acc[i][3]);
        }
    }
}

// Lean GCN gather: out = tanh(dinv_d * sum dinv_s*Y[s] + b), fp16 I/O
__global__ __launch_bounds__(256) void k_gcn_gather(
        const int* __restrict__ rowptr2, const u16* __restrict__ csr2,
        const float* __restrict__ dinv, const __half* __restrict__ Y,
        const float* __restrict__ bias, __half* __restrict__ Bout) {
    int dg = blockIdx.x * 4 + (threadIdx.x >> 6);
    int u = threadIdx.x & 63;
    if (dg >= 2 * NN) return;
    int br = dg >= NN;
    int d = dg - br * NN;
    const int* rp = rowptr2 + br * (NN + 1);
    const u16* cs = csr2 + br * NET;
    int nb = br * NN;
    int beg = rp[d], end = rp[d + 1];
    float a0 = 0.f, a1 = 0.f, a2 = 0.f, a3 = 0.f;
    int i = beg;
    for (; i + 4 <= end; i += 4) {
        int s0 = nb + cs[i], s1 = nb + cs[i + 1], s2 = nb + cs[i + 2], s3 = nb + cs[i + 3];
        a0 += __half2float(Y[(size_t)s0 * 64 + u]) * dinv[s0];
        a1 += __half2float(Y[(size_t)s1 * 64 + u]) * dinv[s1];
        a2 += __half2float(Y[(size_t)s2 * 64 + u]) * dinv[s2];
        a3 += __half2float(Y[(size_t)s3 * 64 + u]) * dinv[s3];
    }
    for (; i < end; i++) { int s = nb + cs[i]; a0 += __half2float(Y[(size_t)s * 64 + u]) * dinv[s]; }
    float h = ((a0 + a1) + (a2 + a3)) * dinv[dg];
    Bout[(size_t)dg * 64 + u] = __float2half(fast_tanh(h + bias[u]));
}

// MLP (64->64 tanh ->32 tanh ->1) + mean-pool. Node-major LDS, fp16 weights,
// segmented-run pool atomics (batch sorted -> ~1-2 atomics per 64-node tile).
__global__ __launch_bounds__(256) void k_mlp_pool(
        const __half* __restrict__ X,
        const int* __restrict__ batch_a, const int* __restrict__ batch_b,
        const float* __restrict__ W1, const float* __restrict__ b1,
        const float* __restrict__ W2, const float* __restrict__ b2,
        const float* __restrict__ W3, const float* __restrict__ b3,
        float* __restrict__ pool) {
    __shared__ __half sW1[64 * 64];
    __shared__ __half sW2[64 * 32];
    __shared__ float sX[64 * XS];    // X tile node-major; reused for Y1
    __shared__ float sP[64 * 9];     // layer-3 partials (stride 9: odd, conflict-free)
    __shared__ float sW3[32], sb1[64], sb2[32];
    __shared__ int sKey[64];
    __shared__ float sVal[64];
    int t = threadIdx.x;
    for (int i = t; i < 4096; i += 256) sW1[i] = __float2half(W1[i]);
    for (int i = t; i < 2048; i += 256) sW2[i] = __float2half(W2[i]);
    if (t < 64) sb1[t] = b1[t];
    if (t < 32) { sW3[t] = W3[t]; sb2[t] = b2[t]; }
    float bb3 = b3[0];
    int base = blockIdx.x * 64;
    load_tile_NM(X, base, sX, t);
    __syncthreads();
    // ---- layer 1: 64 -> 64, 4x4 tile
    int tx = t & 15, ty = t >> 4;
    float acc[4][4];
#pragma unroll
    for (int i = 0; i < 4; i++)
#pragma unroll
        for (int j = 0; j < 4; j++) acc[i][j] = sb1[4 * tx + j];
#pragma unroll 4
    for (int k = 0; k < 64; k++) {
        const __half2* wp = (const __half2*)&sW1[k * 64 + 4 * tx];
        float2 wa = __half22float2(wp[0]);
        float2 wb = __half22float2(wp[1]);
        float x0 = sX[(4 * ty + 0) * XS + k];
        float x1 = sX[(4 * ty + 1) * XS + k];
        float x2 = sX[(4 * ty + 2) * XS + k];
        float x3 = sX[(4 * ty + 3) * XS + k];
        acc[0][0] += x0 * wa.x; acc[0][1] += x0 * wa.y; acc[0][2] += x0 * wb.x; acc[0][3] += x0 * wb.y;
        acc[1][0] += x1 * wa.x; acc[1][1] += x1 * wa.y; acc[1][2] += x1 * wb.x; acc[1][3] += x1 * wb.y;
        acc[2][0] += x2 * wa.x; acc[2][1] += x2 * wa.y; acc[2][2] += x2 * wb.x; acc[2][3] += x2 * wb.y;
        acc[3][0] += x3 * wa.x; acc[3][1] += x3 * wa.y; acc[3][2] += x3 * wb.x; acc[3][3] += x3 * wb.y;
    }
    __syncthreads();  // all layer-1 reads of sX done
    // write tanh back node-major as contiguous float4 (feats 4tx..4tx+3)
#pragma unroll
    for (int i = 0; i < 4; i++) {
        float4 o = make_float4(fast_tanh(acc[i][0]), fast_tanh(acc[i][1]),
                               fast_tanh(acc[i][2]), fast_tanh(acc[i][3]));
        *(float4*)&sX[(4 * ty + i) * XS + 4 * tx] = o;
    }
    __syncthreads();
    // ---- layer 2: 64 -> 32, 2x4 tile (tx2: 8 feat quads, ty2: 32 node pairs)
    int tx2 = t & 7, ty2 = t >> 3;
    float a2_[2][4];
#pragma unroll
    for (int i = 0; i < 2; i++)
#pragma unroll
        for (int j = 0; j < 4; j++) a2_[i][j] = sb2[4 * tx2 + j];
#pragma unroll 4
    for (int k = 0; k < 64; k++) {
        const __half2* wp = (const __half2*)&sW2[k * 32 + 4 * tx2];
        float2 wa = __half22float2(wp[0]);
        float2 wb = __half22float2(wp[1]);
        float x0 = sX[(2 * ty2) * XS + k];
        float x1 = sX[(2 * ty2 + 1) * XS + k];
        a2_[0][0] += x0 * wa.x; a2_[0][1] += x0 * wa.y; a2_[0][2] += x0 * wb.x; a2_[0][3] += x0 * wb.y;
        a2_[1][0] += x1 * wa.x; a2_[1][1] += x1 * wa.y; a2_[1][2] += x1 * wb.x; a2_[1][3] += x1 * wb.y;
    }
    // ---- layer 3 partials
#pragma unroll
    for (int i = 0; i < 2; i++) {
        float p = fast_tanh(a2_[i][0]) * sW3[4 * tx2]
                + fast_tanh(a2_[i][1]) * sW3[4 * tx2 + 1]
                + fast_tanh(a2_[i][2]) * sW3[4 * tx2 + 2]
                + fast_tanh(a2_[i][3]) * sW3[4 * tx2 + 3];
        sP[(2 * ty2 + i) * 9 + tx2] = p;
    }
    __syncthreads();
    // ---- per-node reduce + segmented-run pool (wave 0 only; in-wave LDS order)
    if (t < 64) {
        int n = base + t;
        bool valid = n < 2 * NN;
        int br = n >= NN;
        int g = valid ? (br ? batch_b[n - NN] : batch_a[n]) : -1;
        int key = valid ? (br * 4096 + g) : -1;
        float s0 = sP[t * 9 + 0] + sP[t * 9 + 1] + sP[t * 9 + 2] + sP[t * 9 + 3];
        float s1 = sP[t * 9 + 4] + sP[t * 9 + 5] + sP[t * 9 + 6] + sP[t * 9 + 7];
        sKey[t] = key;
        sVal[t] = s0 + s1 + bb3;
        // wave-synchronous: writes above complete (program order) before reads
        if (valid && (t == 0 || sKey[t - 1] != key)) {
            float sum = 0.f;
            int cnt = 0;
            for (int j = t; j < 64 && sKey[j] == key; j++) { sum += sVal[j]; cnt++; }
            float* bin = pool + br * 2 * NG;
            atomicAdd(&bin[g], sum);
            atomicAdd(&bin[NG + g], (float)cnt);
        }
    }
}

// pool layout: [sa(NG), ca(NG), sb(NG), cb(NG)]
__global__ void k_final(const float* __restrict__ pool, float* __restrict__ out) {
    int g = blockIdx.x * 256 + threadIdx.x;
    if (g >= NG) return;
    float ua = pool[g] / fmaxf(pool[NG + g], 1.f);
    float ub = pool[2 * NG + g] / fmaxf(pool[3 * NG + g], 1.f);
    float z = ub - ua;
    out[g] = 1.f / (1.f + __expf(-z));
}

extern "C" void kernel_launch(void* const* d_in, const int* in_sizes, int n_in,
                              void* d_out, int out_size, void* d_ws, size_t ws_size,
                              hipStream_t stream) {
    const float* x_a = (const float*)d_in[0];
    const float* x_b = (const float*)d_in[1];
    const int* ei_a = (const int*)d_in[2];
    const int* ei_b = (const int*)d_in[3];
    const int* batch_a = (const int*)d_in[4];
    const int* batch_b = (const int*)d_in[5];
    const float* Wg   = (const float*)d_in[6];
    const float* avs  = (const float*)d_in[7];
    const float* avd  = (const float*)d_in[8];
    const float* bg   = (const float*)d_in[9];
    const float* Wgcn = (const float*)d_in[10];
    const float* bgcn = (const float*)d_in[11];
    const float* W1 = (const float*)d_in[12];
    const float* b1 = (const float*)d_in[13];
    const float* W2 = (const float*)d_in[14];
    const float* b2 = (const float*)d_in[15];
    const float* W3 = (const float*)d_in[16];
    const float* b3 = (const float*)d_in[17];

    char* w = (char*)d_ws;
    __half* A2 = (__half*)w;          w += (size_t)2 * NN * 64 * 2;
    __half* B2 = (__half*)w;          w += (size_t)2 * NN * 64 * 2;
    float* als2 = (float*)w;          w += (size_t)2 * NN * 4;
    float* ald2 = (float*)w;          w += (size_t)2 * NN * 4;
    float* dinv2 = (float*)w;         w += (size_t)2 * NN * 4;
    float* pool = (float*)w;          w += (size_t)4 * NG * 4;
    int* cnt2 = (int*)w;              w += (size_t)2 * NN * 4;
    int* rowptr2 = (int*)w;           w += (size_t)2 * (NN + 1) * 4;
    int* cursor2 = (int*)w;           w += (size_t)2 * NN * 4;
    int* partial = (int*)w;           w += (size_t)2 * NCH * 4;
    u16* csr2 = (u16*)w;

    dim3 blk(256);
    const int gE2 = (2 * NET + 255) / 256;

    hipMemsetAsync(cnt2, 0, 2 * NN * sizeof(int), stream);
    k_deg<<<gE2, blk, 0, stream>>>(ei_a, ei_b, cnt2);
    k_scan1<<<2 * NCH, dim3(512), 0, stream>>>(cnt2, partial);
    k_scan2<<<1, blk, 0, stream>>>(partial, rowptr2, pool);
    k_scan3<<<2 * NCH, dim3(512), 0, stream>>>(cnt2, partial, rowptr2, cursor2, dinv2);
    k_scatter<<<2048, blk, 0, stream>>>(ei_a, ei_b, cursor2, csr2);

    k_gat_input<<<GN4, blk, 0, stream>>>(x_a, x_b, Wg, avs, avd, A2, als2, ald2);
    k_gat_csr<<<GN4, blk, 0, stream>>>(rowptr2, csr2, als2, ald2, A2, bg, B2);
    k_lin_tile<<<NT2, blk, 0, stream>>>(B2, Wgcn, A2);
    k_gcn_gather<<<GN4, blk, 0, stream>>>(rowptr2, csr2, dinv2, A2, bgcn, B2);
    k_lin_tile<<<NT2, blk, 0, stream>>>(B2, Wgcn + 64 * 64, A2);
    k_gcn_gather<<<GN4, blk, 0, stream>>>(rowptr2, csr2, dinv2, A2, bgcn + 64, B2);
    k_mlp_pool<<<NT2, blk, 0, stream>>>(B2, batch_a, batch_b, W1, b1, W2, b2, W3, b3, pool);

    k_final<<<(NG + 255) / 256, blk, 0, stream>>>(pool, (float*)d_out);
}

// Round 12
// 518.787 us; speedup vs baseline: 3.2812x; 1.0938x over previous
//
#include <hip/hip_runtime.h>
#include <hip/hip_fp16.h>
#include <math.h>

#define NN 50000
#define NE 800000
#define NG 512
#define NET (NE + NN)            // edges + self loops
#define NCH ((NN + 511) / 512)   // 98 scan chunks per branch
#define NT2 ((2 * NN + 63) / 64) // 1563 64-node tiles over both branches
#define GN4 ((2 * NN + 3) / 4)   // wave-per-node grids, both branches
#define XS 68                    // node-major LDS stride (x4B: 2-way banks max)
#define PART 6250                // NN / 8 — dst slice per XCD

typedef unsigned short u16;

__device__ __forceinline__ float wsum64(float v) {
#pragma unroll
    for (int o = 32; o > 0; o >>= 1) v += __shfl_down(v, o, 64);
    return v;
}

__device__ __forceinline__ float fast_tanh(float x) {
    return 1.f - 2.f / (__expf(2.f * x) + 1.f);
}

// ---------------- CSR build (both branches) ----------------

__global__ void k_deg(const int* __restrict__ eia, const int* __restrict__ eib,
                      int* __restrict__ cnt2) {
    int e = blockIdx.x * 256 + threadIdx.x;
    if (e >= 2 * NET) return;
    int br = e >= NET;
    int el = e - br * NET;
    const int* ei = br ? eib : eia;
    int d = (el < NE) ? ei[NE + el] : (el - NE);
    atomicAdd(&cnt2[br * NN + d], 1);
}

__global__ void k_scan1(const int* __restrict__ cnt2, int* __restrict__ partial) {
    int b = blockIdx.x;
    int br = b >= NCH, c = b - (br ? NCH : 0);
    int i = c * 512 + threadIdx.x;
    int v = (i < NN) ? cnt2[br * NN + i] : 0;
    __shared__ int sp[8];
    int lane = threadIdx.x & 63, w = threadIdx.x >> 6;
#pragma unroll
    for (int o = 32; o > 0; o >>= 1) v += __shfl_down(v, o, 64);
    if (lane == 0) sp[w] = v;
    __syncthreads();
    if (threadIdx.x == 0) {
        int s = 0;
#pragma unroll
        for (int k = 0; k < 8; k++) s += sp[k];
        partial[b] = s;
    }
}

__global__ void k_scan2(int* __restrict__ partial, int* __restrict__ rowptr2,
                        float* __restrict__ pool) {
    __shared__ int s[2 * NCH];
    int t = threadIdx.x;  // 256
    for (int i = t; i < 4 * NG; i += 256) pool[i] = 0.f;
    for (int i = t; i < 2 * NCH; i += 256) s[i] = partial[i];
    __syncthreads();
    if (t < 2) {
        int run = 0;
        for (int i = 0; i < NCH; i++) { int v = s[t * NCH + i]; s[t * NCH + i] = run; run += v; }
        rowptr2[t * (NN + 1) + NN] = run;
    }
    __syncthreads();
    for (int i = t; i < 2 * NCH; i += 256) partial[i] = s[i];
}

__global__ void k_scan3(const int* __restrict__ cnt2, const int* __restrict__ partial,
                        int* __restrict__ rowptr2, int* __restrict__ cursor2,
                        float* __restrict__ dinv2) {
    __shared__ int s[512];
    int b = blockIdx.x;
    int br = b >= NCH, c = b - (br ? NCH : 0);
    int t = threadIdx.x;
    int i = c * 512 + t;
    int v = (i < NN) ? cnt2[br * NN + i] : 0;
    s[t] = v;
    __syncthreads();
    for (int o = 1; o < 512; o <<= 1) {
        int add = (t >= o) ? s[t - o] : 0;
        __syncthreads();
        s[t] += add;
        __syncthreads();
    }
    if (i < NN) {
        int excl = s[t] - v + partial[b];
        rowptr2[br * (NN + 1) + i] = excl;
        cursor2[br * NN + i] = excl;
        dinv2[br * NN + i] = v > 0 ? rsqrtf((float)v) : 0.f;
    }
}

// XCD-partitioned scatter (round 9): slice p's csr2 region is only dirtied by
// XCD p's L2 -> lines written back once.
__global__ __launch_bounds__(256) void k_scatter(
        const int* __restrict__ eia, const int* __restrict__ eib,
        int* __restrict__ cursor2, u16* __restrict__ csr2) {
    int p = blockIdx.x & 7;
    int blk = blockIdx.x >> 3;
    int nblk = gridDim.x >> 3;
    int lo = p * PART, hi = lo + PART;
    for (int e = blk * 256 + threadIdx.x; e < 2 * NET; e += nblk * 256) {
        int br = e >= NET;
        int el = e - br * NET;
        const int* ei = br ? eib : eia;
        int d = (el < NE) ? ei[NE + el] : (el - NE);
        if (d >= lo && d < hi) {
            int s = (el < NE) ? ei[el] : d;
            int pos = atomicAdd(&cursor2[br * NN + d], 1);
            csr2[br * NET + pos] = (u16)s;
        }
    }
}

// ---------------- node-level kernels (node id in [0,2*NN)) ----

__global__ void k_gat_input(const float* __restrict__ xa, const float* __restrict__ xb,
                            const float* __restrict__ Wg,
                            const float* __restrict__ avs, const float* __restrict__ avd,
                            __half* __restrict__ A, float* __restrict__ als,
                            float* __restrict__ ald) {
    __shared__ float sW[9 * 64];
    __shared__ float sas[64], sad[64];
    int t = threadIdx.x;
    for (int i = t; i < 9 * 64; i += 256) sW[i] = Wg[i];
    if (t < 64) { sas[t] = avs[t]; sad[t] = avd[t]; }
    __syncthreads();
    int n = blockIdx.x * 4 + (t >> 6);
    int u = t & 63;
    if (n >= 2 * NN) return;
    const float* xp = (n < NN) ? &xa[(size_t)n * 9] : &xb[(size_t)(n - NN) * 9];
    float h = 0.f;
#pragma unroll
    for (int f = 0; f < 9; f++) h += xp[f] * sW[f * 64 + u];
    A[(size_t)n * 64 + u] = __float2half(h);
    float ps = wsum64(h * sas[u]);
    float pd = wsum64(h * sad[u]);
    if (u == 0) { als[n] = ps; ald[n] = pd; }
}

// GAT two-phase: per 64-edge chunk, phase A computes edge weights lane-parallel
// (coalesced index load, ONE exp per edge instead of 64), phase B shfl-broadcasts
// (s_j, w_j) and does the feature-parallel gather-FMA. No max-stab (|e|<~25).
__global__ __launch_bounds__(256) void k_gat_csr(
        const int* __restrict__ rowptr2, const u16* __restrict__ csr2,
        const float* __restrict__ als, const float* __restrict__ ald,
        const __half* __restrict__ A, const float* __restrict__ bias,
        __half* __restrict__ B) {
    int dg = blockIdx.x * 4 + (threadIdx.x >> 6);
    int u = threadIdx.x & 63;
    if (dg >= 2 * NN) return;
    int br = dg >= NN;
    int d = dg - br * NN;
    const int* rp = rowptr2 + br * (NN + 1);
    const u16* cs = csr2 + br * NET;
    int nb = br * NN;
    int beg = rp[d], end = rp[d + 1];
    float ad = ald[dg];
    float acc = 0.f;
    float denl = 0.f;
    for (int c = beg; c < end; c += 64) {
        // phase A: lane-parallel edge weights (coalesced cs load, 1 exp/edge)
        int idx = c + u;
        int s = 0;
        float w = 0.f;
        if (idx < end) {
            s = nb + cs[idx];
            float v = als[s] + ad;
            w = __expf(fmaxf(v, 0.2f * v));
        }
        denl += w;
        // phase B: feature-parallel aggregate, (s,w) broadcast by shfl
        int m = end - c; if (m > 64) m = 64;
        int j = 0;
        for (; j + 4 <= m; j += 4) {
            int s0 = __shfl(s, j, 64),     s1 = __shfl(s, j + 1, 64);
            int s2 = __shfl(s, j + 2, 64), s3 = __shfl(s, j + 3, 64);
            float w0 = __shfl(w, j, 64),     w1 = __shfl(w, j + 1, 64);
            float w2 = __shfl(w, j + 2, 64), w3 = __shfl(w, j + 3, 64);
            float f0 = __half2float(A[(size_t)s0 * 64 + u]);
            float f1 = __half2float(A[(size_t)s1 * 64 + u]);
            float f2 = __half2float(A[(size_t)s2 * 64 + u]);
            float f3 = __half2float(A[(size_t)s3 * 64 + u]);
            acc += f0 * w0 + f1 * w1 + f2 * w2 + f3 * w3;
        }
        for (; j < m; j++) {
            int sj = __shfl(s, j, 64);
            float wj = __shfl(w, j, 64);
            acc += __half2float(A[(size_t)sj * 64 + u]) * wj;
        }
    }
    float den = wsum64(denl);
    den = __shfl(den, 0, 64);
    B[(size_t)dg * 64 + u] = __float2half(fast_tanh(acc / den + bias[u]));
}

// Stage 64-node fp16 tile into LDS node-major: sX[node * XS + feat].
__device__ __forceinline__ void load_tile_NM(const __half* __restrict__ X, int base,
                                             float* sX, int t) {
    const __half2* X2 = (const __half2*)X;
    for (int i = t; i < 2048; i += 256) {
        int node = i >> 5, p = i & 31;
        float2 v;
        if (base + node < 2 * NN) v = __half22float2(X2[(size_t)(base + node) * 32 + p]);
        else v = make_float2(0.f, 0.f);
        *(float2*)&sX[node * XS + 2 * p] = v;
    }
}

// Dense Y = dinv[n] * (X @ W), 64-node tile, 4x4 blocking, fp16 weights/IO.
// Pre-scaling by dinv (exact: sum_s dinv_s*(XW)_s == sum_s (dinv*XW)_s) lets
// the gather kernel skip the per-edge random dinv[s] load.
__global__ __launch_bounds__(256) void k_lin_tile(
        const __half* __restrict__ X, const float* __restrict__ W,
        const float* __restrict__ dinv, __half* __restrict__ Y) {
    __shared__ __half sW[64 * 64];
    __shared__ float sX[64 * XS];
    int t = threadIdx.x;
    for (int i = t; i < 4096; i += 256) sW[i] = __float2half(W[i]);
    int base = blockIdx.x * 64;
    load_tile_NM(X, base, sX, t);
    __syncthreads();
    int tx = t & 15, ty = t >> 4;
    float acc[4][4];
#pragma unroll
    for (int i = 0; i < 4; i++)
#pragma unroll
        for (int j = 0; j < 4; j++) acc[i][j] = 0.f;
#pragma unroll 4
    for (int k = 0; k < 64; k++) {
        const __half2* wp = (const __half2*)&sW[k * 64 + 4 * tx];
        float2 wa = __half22float2(wp[0]);
        float2 wb = __half22float2(wp[1]);
        float x0 = sX[(4 * ty + 0) * XS + k];
        float x1 = sX[(4 * ty + 1) * XS + k];
        float x2 = sX[(4 * ty + 2) * XS + k];
        float x3 = sX[(4 * ty + 3) * XS + k];
        acc[0][0] += x0 * wa.x; acc[0][1] += x0 * wa.y; acc[0][2] += x0 * wb.x; acc[0][3] += x0 * wb.y;
        acc[1][0] += x1 * wa.x; acc[1][1] += x1 * wa.y; acc[1][2] += x1 * wb.x; acc[1][3] += x1 * wb.y;
        acc[2][0] += x2 * wa.x; acc[2][1] += x2 * wa.y; acc[2][2] += x2 * wb.x; acc[2][3] += x2 * wb.y;
        acc[3][0] += x3 * wa.x; acc[3][1] += x3 * wa.y; acc[3][2] += x3 * wb.x; acc[3][3] += x3 * wb.y;
    }
#pragma unroll
    for (int i = 0; i < 4; i++) {
        int n = base + 4 * ty + i;
        if (n < 2 * NN) {
            float dv = dinv[n];
            __half2* Y2 = (__half2*)&Y[(size_t)n * 64 + 4 * tx];
            Y2[0] = __floats2half2_rn(acc[i][0] * dv, acc[i][1] * dv);
            Y2[1] = __floats2half2_rn(acc[i][2] * dv, acc[i][3] * dv);
        }
    }
}

// Lean GCN gather on pre-scaled Y: out = tanh(dinv_d * sum Y[s] + b).
// Chunked coalesced index load + shfl broadcast.
__global__ __launch_bounds__(256) void k_gcn_gather(
        const int* __restrict__ rowptr2, const u16* __restrict__ csr2,
        const float* __restrict__ dinv, const __half* __restrict__ Y,
        const float* __restrict__ bias, __half* __restrict__ Bout) {
    int dg = blockIdx.x * 4 + (threadIdx.x >> 6);
    int u = threadIdx.x & 63;
    if (dg >= 2 * NN) return;
    int br = dg >= NN;
    int d = dg - br * NN;
    const int* rp = rowptr2 + br * (NN + 1);
    const u16* cs = csr2 + br * NET;
    int nb = br * NN;
    int beg = rp[d], end = rp[d + 1];
    float a0 = 0.f, a1 = 0.f, a2 = 0.f, a3 = 0.f;
    for (int c = beg; c < end; c += 64) {
        int idx = c + u;
        int s = (idx < end) ? nb + cs[idx] : 0;   // coalesced
        int m = end - c; if (m > 64) m = 64;
        int j = 0;
        for (; j + 4 <= m; j += 4) {
            int s0 = __shfl(s, j, 64),     s1 = __shfl(s, j + 1, 64);
            int s2 = __shfl(s, j + 2, 64), s3 = __shfl(s, j + 3, 64);
            a0 += __half2float(Y[(size_t)s0 * 64 + u]);
            a1 += __half2float(Y[(size_t)s1 * 64 + u]);
            a2 += __half2float(Y[(size_t)s2 * 64 + u]);
            a3 += __half2float(Y[(size_t)s3 * 64 + u]);
        }
        for (; j < m; j++) {
            int sj = __shfl(s, j, 64);
            a0 += __half2float(Y[(size_t)sj * 64 + u]);
        }
    }
    float h = ((a0 + a1) + (a2 + a3)) * dinv[dg];
    Bout[(size_t)dg * 64 + u] = __float2half(fast_tanh(h + bias[u]));
}

// MLP (64->64 tanh ->32 tanh ->1) + mean-pool. Node-major LDS, fp16 weights,
// segmented-run pool atomics.
__global__ __launch_bounds__(256) void k_mlp_pool(
        const __half* __restrict__ X,
        const int* __restrict__ batch_a, const int* __restrict__ batch_b,
        const float* __restrict__ W1, const float* __restrict__ b1,
        const float* __restrict__ W2, const float* __restrict__ b2,
        const float* __restrict__ W3, const float* __restrict__ b3,
        float* __restrict__ pool) {
    __shared__ __half sW1[64 * 64];
    __shared__ __half sW2[64 * 32];
    __shared__ float sX[64 * XS];
    __shared__ float sP[64 * 9];
    __shared__ float sW3[32], sb1[64], sb2[32];
    __shared__ int sKey[64];
    __shared__ float sVal[64];
    int t = threadIdx.x;
    for (int i = t; i < 4096; i += 256) sW1[i] = __float2half(W1[i]);
    for (int i = t; i < 2048; i += 256) sW2[i] = __float2half(W2[i]);
    if (t < 64) sb1[t] = b1[t];
    if (t < 32) { sW3[t] = W3[t]; sb2[t] = b2[t]; }
    float bb3 = b3[0];
    int base = blockIdx.x * 64;
    load_tile_NM(X, base, sX, t);
    __syncthreads();
    int tx = t & 15, ty = t >> 4;
    float acc[4][4];
#pragma unroll
    for (int i = 0; i < 4; i++)
#pragma unroll
        for (int j = 0; j < 4; j++) acc[i][j] = sb1[4 * tx + j];
#pragma unroll 4
    for (int k = 0; k < 64; k++) {
        const __half2* wp = (const __half2*)&sW1[k * 64 + 4 * tx];
        float2 wa = __half22float2(wp[0]);
        float2 wb = __half22float2(wp[1]);
        float x0 = sX[(4 * ty + 0) * XS + k];
        float x1 = sX[(4 * ty + 1) * XS + k];
        float x2 = sX[(4 * ty + 2) * XS + k];
        float x3 = sX[(4 * ty + 3) * XS + k];
        acc[0][0] += x0 * wa.x; acc[0][1] += x0 * wa.y; acc[0][2] += x0 * wb.x; acc[0][3] += x0 * wb.y;
        acc[1][0] += x1 * wa.x; acc[1][1] += x1 * wa.y; acc[1][2] += x1 * wb.x; acc[1][3] += x1 * wb.y;
        acc[2][0] += x2 * wa.x; acc[2][1] += x2 * wa.y; acc[2][2] += x2 * wb.x; acc[2][3] += x2 * wb.y;
        acc[3][0] += x3 * wa.x; acc[3][1] += x3 * wa.y; acc[3][2] += x3 * wb.x; acc[3][3] += x3 * wb.y;
    }
    __syncthreads();
#pragma unroll
    for (int i = 0; i < 4; i++) {
        float4 o = make_float4(fast_tanh(acc[i][0]), fast_tanh(acc[i][1]),
                               fast_tanh(acc[i][2]), fast_tanh(acc[i][3]));
        *(float4*)&sX[(4 * ty + i) * XS + 4 * tx] = o;
    }
    __syncthreads();
    int tx2 = t & 7, ty2 = t >> 3;
    float a2_[2][4];
#pragma unroll
    for (int i = 0; i < 2; i++)
#pragma unroll
        for (int j = 0; j < 4; j++) a2_[i][j] = sb2[4 * tx2 + j];
#pragma unroll 4
    for (int k = 0; k < 64; k++) {
        const __half2* wp = (const __half2*)&sW2[k * 32 + 4 * tx2];
        float2 wa = __half22float2(wp[0]);
        float2 wb = __half22float2(wp[1]);
        float x0 = sX[(2 * ty2) * XS + k];
        float x1 = sX[(2 * ty2 + 1) * XS + k];
        a2_[0][0] += x0 * wa.x; a2_[0][1] += x0 * wa.y; a2_[0][2] += x0 * wb.x; a2_[0][3] += x0 * wb.y;
        a2_[1][0] += x1 * wa.x; a2_[1][1] += x1 * wa.y; a2_[1][2] += x1 * wb.x; a2_[1][3] += x1 * wb.y;
    }
#pragma unroll
    for (int i = 0; i < 2; i++) {
        float p = fast_tanh(a2_[i][0]) * sW3[4 * tx2]
                + fast_tanh(a2_[i][1]) * sW3[4 * tx2 + 1]
                + fast_tanh(a2_[i][2]) * sW3[4 * tx2 + 2]
                + fast_tanh(a2_[i][3]) * sW3[4 * tx2 + 3];
        sP[(2 * ty2 + i) * 9 + tx2] = p;
    }
    __syncthreads();
    if (t < 64) {
        int n = base + t;
        bool valid = n < 2 * NN;
        int br = n >= NN;
        int g = valid ? (br ? batch_b[n - NN] : batch_a[n]) : -1;
        int key = valid ? (br * 4096 + g) : -1;
        float s0 = sP[t * 9 + 0] + sP[t * 9 + 1] + sP[t * 9 + 2] + sP[t * 9 + 3];
        float s1 = sP[t * 9 + 4] + sP[t * 9 + 5] + sP[t * 9 + 6] + sP[t * 9 + 7];
        sKey[t] = key;
        sVal[t] = s0 + s1 + bb3;
        if (valid && (t == 0 || sKey[t - 1] != key)) {
            float sum = 0.f;
            int cnt = 0;
            for (int j = t; j < 64 && sKey[j] == key; j++) { sum += sVal[j]; cnt++; }
            float* bin = pool + br * 2 * NG;
            atomicAdd(&bin[g], sum);
            atomicAdd(&bin[NG + g], (float)cnt);
        }
    }
}

// pool layout: [sa(NG), ca(NG), sb(NG), cb(NG)]
__global__ void k_final(const float* __restrict__ pool, float* __restrict__ out) {
    int g = blockIdx.x * 256 + threadIdx.x;
    if (g >= NG) return;
    float ua = pool[g] / fmaxf(pool[NG + g], 1.f);
    float ub = pool[2 * NG + g] / fmaxf(pool[3 * NG + g], 1.f);
    float z = ub - ua;
    out[g] = 1.f / (1.f + __expf(-z));
}

extern "C" void kernel_launch(void* const* d_in, const int* in_sizes, int n_in,
                              void* d_out, int out_size, void* d_ws, size_t ws_size,
                              hipStream_t stream) {
    const float* x_a = (const float*)d_in[0];
    const float* x_b = (const float*)d_in[1];
    const int* ei_a = (const int*)d_in[2];
    const int* ei_b = (const int*)d_in[3];
    const int* batch_a = (const int*)d_in[4];
    const int* batch_b = (const int*)d_in[5];
    const float* Wg   = (const float*)d_in[6];
    const float* avs  = (const float*)d_in[7];
    const float* avd  = (const float*)d_in[8];
    const float* bg   = (const float*)d_in[9];
    const float* Wgcn = (const float*)d_in[10];
    const float* bgcn = (const float*)d_in[11];
    const float* W1 = (const float*)d_in[12];
    const float* b1 = (const float*)d_in[13];
    const float* W2 = (const float*)d_in[14];
    const float* b2 = (const float*)d_in[15];
    const float* W3 = (const float*)d_in[16];
    const float* b3 = (const float*)d_in[17];

    char* w = (char*)d_ws;
    __half* A2 = (__half*)w;          w += (size_t)2 * NN * 64 * 2;
    __half* B2 = (__half*)w;          w += (size_t)2 * NN * 64 * 2;
    float* als2 = (float*)w;          w += (size_t)2 * NN * 4;
    float* ald2 = (float*)w;          w += (size_t)2 * NN * 4;
    float* dinv2 = (float*)w;         w += (size_t)2 * NN * 4;
    float* pool = (float*)w;          w += (size_t)4 * NG * 4;
    int* cnt2 = (int*)w;              w += (size_t)2 * NN * 4;
    int* rowptr2 = (int*)w;           w += (size_t)2 * (NN + 1) * 4;
    int* cursor2 = (int*)w;           w += (size_t)2 * NN * 4;
    int* partial = (int*)w;           w += (size_t)2 * NCH * 4;
    u16* csr2 = (u16*)w;

    dim3 blk(256);
    const int gE2 = (2 * NET + 255) / 256;

    hipMemsetAsync(cnt2, 0, 2 * NN * sizeof(int), stream);
    k_deg<<<gE2, blk, 0, stream>>>(ei_a, ei_b, cnt2);
    k_scan1<<<2 * NCH, dim3(512), 0, stream>>>(cnt2, partial);
    k_scan2<<<1, blk, 0, stream>>>(partial, rowptr2, pool);
    k_scan3<<<2 * NCH, dim3(512), 0, stream>>>(cnt2, partial, rowptr2, cursor2, dinv2);
    k_scatter<<<2048, blk, 0, stream>>>(ei_a, ei_b, cursor2, csr2);

    k_gat_input<<<GN4, blk, 0, stream>>>(x_a, x_b, Wg, avs, avd, A2, als2, ald2);
    k_gat_csr<<<GN4, blk, 0, stream>>>(rowptr2, csr2, als2, ald2, A2, bg, B2);
    k_lin_tile<<<NT2, blk, 0, stream>>>(B2, Wgcn, dinv2, A2);
    k_gcn_gather<<<GN4, blk, 0, stream>>>(rowptr2, csr2, dinv2, A2, bgcn, B2);
    k_lin_tile<<<NT2, blk, 0, stream>>>(B2, Wgcn + 64 * 64, dinv2, A2);
    k_gcn_gather<<<GN4, blk, 0, stream>>>(rowptr2, csr2, dinv2, A2, bgcn + 64, B2);
    k_mlp_pool<<<NT2, blk, 0, stream>>>(B2, batch_a, batch_b, W1, b1, W2, b2, W3, b3, pool);

    k_final<<<(NG + 255) / 256, blk, 0, stream>>>(pool, (float*)d_out);
}